// Round 1
// baseline (1562.366 us; speedup 1.0000x reference)
//
#include <hip/hip_runtime.h>

constexpr int Bb = 4;
constexpr int Ss = 2048;
constexpr int NTOK = Bb * Ss; // 8192

// ---------------------------------------------------------------------------
// GEMM: C[m, coff+n] = act(sum_k A[m,k] * W[n,k] + bias[n])
// A: [M,K] row-major, W: [N,K] row-major (i.e. computes A @ W^T), C row stride ldc.
// BM=128, BN=64, BK=32; 256 threads; each thread 8x4 outputs.
// LDS stored K-major (As[k][m], Ws[k][n]) so inner loop reads are float4.
// ---------------------------------------------------------------------------
template<bool SILU>
__global__ __launch_bounds__(256) void gemm_nt(
    const float* __restrict__ A, const float* __restrict__ W,
    const float* __restrict__ bias, float* __restrict__ C,
    int K, int ldc, int coff)
{
    constexpr int BM = 128, BN = 64, BK = 32;
    __shared__ float As[BK][BM + 4];
    __shared__ float Ws[BK][BN + 4];
    const int tid = threadIdx.x;
    const int tx = tid & 15;   // n-sub: n = tx*4
    const int ty = tid >> 4;   // m-sub: m = ty*8
    const int n0 = blockIdx.x * BN;
    const int m0 = blockIdx.y * BM;

    float acc[8][4];
#pragma unroll
    for (int i = 0; i < 8; i++)
#pragma unroll
        for (int j = 0; j < 4; j++) acc[i][j] = 0.f;

    for (int k0 = 0; k0 < K; k0 += BK) {
        __syncthreads();
        // stage A tile: 128 rows x 32 cols = 1024 float4, 4 per thread (transposed into LDS)
#pragma unroll
        for (int i = 0; i < 4; i++) {
            int idx = i * 256 + tid;
            int row = idx >> 3, c4 = idx & 7;
            float4 v = *(const float4*)&A[(size_t)(m0 + row) * K + k0 + c4 * 4];
            As[c4 * 4 + 0][row] = v.x; As[c4 * 4 + 1][row] = v.y;
            As[c4 * 4 + 2][row] = v.z; As[c4 * 4 + 3][row] = v.w;
        }
        // stage W tile: 64 rows x 32 cols = 512 float4, 2 per thread
#pragma unroll
        for (int i = 0; i < 2; i++) {
            int idx = i * 256 + tid;
            int row = idx >> 3, c4 = idx & 7;
            float4 v = *(const float4*)&W[(size_t)(n0 + row) * K + k0 + c4 * 4];
            Ws[c4 * 4 + 0][row] = v.x; Ws[c4 * 4 + 1][row] = v.y;
            Ws[c4 * 4 + 2][row] = v.z; Ws[c4 * 4 + 3][row] = v.w;
        }
        __syncthreads();
#pragma unroll
        for (int kk = 0; kk < BK; kk++) {
            float4 a0 = *(const float4*)&As[kk][ty * 8];
            float4 a1 = *(const float4*)&As[kk][ty * 8 + 4];
            float4 w0 = *(const float4*)&Ws[kk][tx * 4];
            float am[8] = {a0.x, a0.y, a0.z, a0.w, a1.x, a1.y, a1.z, a1.w};
            float wn[4] = {w0.x, w0.y, w0.z, w0.w};
#pragma unroll
            for (int i = 0; i < 8; i++)
#pragma unroll
                for (int j = 0; j < 4; j++)
                    acc[i][j] += am[i] * wn[j];
        }
    }

    const int n = n0 + tx * 4;
    float bz0 = bias[n + 0], bz1 = bias[n + 1], bz2 = bias[n + 2], bz3 = bias[n + 3];
#pragma unroll
    for (int i = 0; i < 8; i++) {
        float4 o;
        o.x = acc[i][0] + bz0; o.y = acc[i][1] + bz1;
        o.z = acc[i][2] + bz2; o.w = acc[i][3] + bz3;
        if (SILU) {
            o.x = o.x / (1.f + __expf(-o.x));
            o.y = o.y / (1.f + __expf(-o.y));
            o.z = o.z / (1.f + __expf(-o.z));
            o.w = o.w / (1.f + __expf(-o.w));
        }
        *(float4*)&C[(size_t)(m0 + ty * 8 + i) * ldc + coff + n] = o;
    }
}

// ---------------------------------------------------------------------------
// Global MHA (flash-style, fp32): 8 heads, hd=32, full S=2048 softmax.
// qkv layout: [B,S,768] (q | k | v each 256 cols; head h = cols h*32..).
// Grid: 256 blocks = (b:4, h:8, qtile:8); block = 128 threads, each owns
// 2 queries (q0 = qt*256+tid, q1 = +128). K/V staged in 64-key LDS tiles.
// ---------------------------------------------------------------------------
__global__ __launch_bounds__(128, 1) void attn_global(
    const float* __restrict__ qkv, float* __restrict__ out)
{
    const int tid = threadIdx.x;
    const int bid = blockIdx.x;
    const int b  = bid >> 6;
    const int h  = (bid >> 3) & 7;
    const int qt = bid & 7;
    const float scale = 0.17677669529663687f; // 1/sqrt(32)

    __shared__ float kt[64][32];
    __shared__ float vt[64][32];

    const int qia = qt * 256 + tid;
    const int qib = qia + 128;

    float qa[32], qb[32], oa[32], ob[32];
    {
        const float* pa = qkv + (size_t)(b * Ss + qia) * 768 + h * 32;
        const float* pb = qkv + (size_t)(b * Ss + qib) * 768 + h * 32;
#pragma unroll
        for (int i = 0; i < 8; i++) {
            float4 va = *(const float4*)&pa[i * 4];
            qa[i * 4 + 0] = va.x; qa[i * 4 + 1] = va.y; qa[i * 4 + 2] = va.z; qa[i * 4 + 3] = va.w;
            float4 vb = *(const float4*)&pb[i * 4];
            qb[i * 4 + 0] = vb.x; qb[i * 4 + 1] = vb.y; qb[i * 4 + 2] = vb.z; qb[i * 4 + 3] = vb.w;
        }
    }
#pragma unroll
    for (int d = 0; d < 32; d++) { oa[d] = 0.f; ob[d] = 0.f; }
    float ma = -1e30f, la = 0.f, mb = -1e30f, lb = 0.f;

    for (int t = 0; t < Ss / 64; t++) {
        __syncthreads();
#pragma unroll
        for (int i = 0; i < 4; i++) {
            int idx = i * 128 + tid;           // 0..511
            int row = idx >> 3, c4 = idx & 7;
            const float* kp = qkv + (size_t)(b * Ss + t * 64 + row) * 768 + 256 + h * 32 + c4 * 4;
            *(float4*)&kt[row][c4 * 4] = *(const float4*)kp;
            *(float4*)&vt[row][c4 * 4] = *(const float4*)(kp + 256);
        }
        __syncthreads();
        for (int kk = 0; kk < 64; kk++) {
            float s0 = 0.f, s1 = 0.f;
#pragma unroll
            for (int d4 = 0; d4 < 8; d4++) {
                float4 kv = *(const float4*)&kt[kk][d4 * 4];
                s0 += qa[d4 * 4 + 0] * kv.x + qa[d4 * 4 + 1] * kv.y
                    + qa[d4 * 4 + 2] * kv.z + qa[d4 * 4 + 3] * kv.w;
                s1 += qb[d4 * 4 + 0] * kv.x + qb[d4 * 4 + 1] * kv.y
                    + qb[d4 * 4 + 2] * kv.z + qb[d4 * 4 + 3] * kv.w;
            }
            s0 *= scale; s1 *= scale;
            if (s0 > ma) {
                float c = __expf(ma - s0); la *= c;
#pragma unroll
                for (int d = 0; d < 32; d++) oa[d] *= c;
                ma = s0;
            }
            if (s1 > mb) {
                float c = __expf(mb - s1); lb *= c;
#pragma unroll
                for (int d = 0; d < 32; d++) ob[d] *= c;
                mb = s1;
            }
            float p0 = __expf(s0 - ma);
            float p1 = __expf(s1 - mb);
            la += p0; lb += p1;
#pragma unroll
            for (int d4 = 0; d4 < 8; d4++) {
                float4 vv = *(const float4*)&vt[kk][d4 * 4];
                oa[d4 * 4 + 0] += p0 * vv.x; oa[d4 * 4 + 1] += p0 * vv.y;
                oa[d4 * 4 + 2] += p0 * vv.z; oa[d4 * 4 + 3] += p0 * vv.w;
                ob[d4 * 4 + 0] += p1 * vv.x; ob[d4 * 4 + 1] += p1 * vv.y;
                ob[d4 * 4 + 2] += p1 * vv.z; ob[d4 * 4 + 3] += p1 * vv.w;
            }
        }
    }
    float ia = 1.f / la, ib = 1.f / lb;
    {
        float* po = out + (size_t)(b * Ss + qia) * 256 + h * 32;
#pragma unroll
        for (int i = 0; i < 8; i++) {
            float4 o;
            o.x = oa[i * 4 + 0] * ia; o.y = oa[i * 4 + 1] * ia;
            o.z = oa[i * 4 + 2] * ia; o.w = oa[i * 4 + 3] * ia;
            *(float4*)&po[i * 4] = o;
        }
    }
    {
        float* po = out + (size_t)(b * Ss + qib) * 256 + h * 32;
#pragma unroll
        for (int i = 0; i < 8; i++) {
            float4 o;
            o.x = ob[i * 4 + 0] * ib; o.y = ob[i * 4 + 1] * ib;
            o.z = ob[i * 4 + 2] * ib; o.w = ob[i * 4 + 3] * ib;
            *(float4*)&po[i * 4] = o;
        }
    }
}

// ---------------------------------------------------------------------------
// Local windowed MHA: 4 heads, hd=64, window 5 (HALF=2).
// One wave per (b, s, h); lane = dim. Shuffle-reduce the 5 dots.
// ---------------------------------------------------------------------------
__global__ __launch_bounds__(256) void attn_local(
    const float* __restrict__ qkv, float* __restrict__ out)
{
    const int lane = threadIdx.x & 63;
    const int w = blockIdx.x * 4 + (threadIdx.x >> 6);
    const int b = w >> 13;         // / 8192
    const int rem = w & 8191;
    const int s = rem >> 2;
    const int h = rem & 3;

    const float q = qkv[(size_t)(b * Ss + s) * 768 + h * 64 + lane];
    float sc[5], vv[5];
#pragma unroll
    for (int j = 0; j < 5; j++) {
        int pos = s + j - 2;
        bool valid = (pos >= 0) && (pos < Ss);
        int cpos = valid ? pos : 0;
        const size_t rb = (size_t)(b * Ss + cpos) * 768;
        float kj = valid ? qkv[rb + 256 + h * 64 + lane] : 0.f;
        vv[j] = valid ? qkv[rb + 512 + h * 64 + lane] : 0.f;
        float p = q * kj;
#pragma unroll
        for (int off = 32; off > 0; off >>= 1) p += __shfl_xor(p, off, 64);
        sc[j] = valid ? p * 0.125f : -1e30f; // 1/sqrt(64)
    }
    float m = sc[0];
#pragma unroll
    for (int j = 1; j < 5; j++) m = fmaxf(m, sc[j]);
    float l = 0.f, o = 0.f;
#pragma unroll
    for (int j = 0; j < 5; j++) {
        float p = __expf(sc[j] - m);
        l += p; o += p * vv[j];
    }
    out[(size_t)(b * Ss + s) * 256 + h * 64 + lane] = o / l;
}

// ---------------------------------------------------------------------------
// out = LayerNorm(a + r) * g + be   over last dim (256). Wave per token.
// ---------------------------------------------------------------------------
__global__ __launch_bounds__(256) void ln_residual(
    const float* __restrict__ a, const float* __restrict__ r,
    const float* __restrict__ g, const float* __restrict__ be,
    float* __restrict__ out)
{
    const int lane = threadIdx.x & 63;
    const int tok = blockIdx.x * 4 + (threadIdx.x >> 6);
    float4 xa = ((const float4*)a)[(size_t)tok * 64 + lane];
    float4 xr = ((const float4*)r)[(size_t)tok * 64 + lane];
    float4 x;
    x.x = xa.x + xr.x; x.y = xa.y + xr.y; x.z = xa.z + xr.z; x.w = xa.w + xr.w;
    float sum = x.x + x.y + x.z + x.w;
#pragma unroll
    for (int off = 32; off > 0; off >>= 1) sum += __shfl_xor(sum, off, 64);
    float mu = sum * (1.f / 256.f);
    float4 c;
    c.x = x.x - mu; c.y = x.y - mu; c.z = x.z - mu; c.w = x.w - mu;
    float sq = c.x * c.x + c.y * c.y + c.z * c.z + c.w * c.w;
#pragma unroll
    for (int off = 32; off > 0; off >>= 1) sq += __shfl_xor(sq, off, 64);
    float rs = rsqrtf(sq * (1.f / 256.f) + 1e-5f);
    float4 gg = ((const float4*)g)[lane];
    float4 bb = ((const float4*)be)[lane];
    float4 o;
    o.x = c.x * rs * gg.x + bb.x; o.y = c.y * rs * gg.y + bb.y;
    o.z = c.z * rs * gg.z + bb.z; o.w = c.w * rs * gg.w + bb.w;
    ((float4*)out)[(size_t)tok * 64 + lane] = o;
}

// ---------------------------------------------------------------------------
extern "C" void kernel_launch(void* const* d_in, const int* in_sizes, int n_in,
                              void* d_out, int out_size, void* d_ws, size_t ws_size,
                              hipStream_t stream)
{
    const float* x      = (const float*)d_in[0];
    const float* g_in_w = (const float*)d_in[1];
    const float* g_in_b = (const float*)d_in[2];
    const float* g_out_w= (const float*)d_in[3];
    const float* g_out_b= (const float*)d_in[4];
    const float* t_in_w = (const float*)d_in[5];
    const float* t_in_b = (const float*)d_in[6];
    const float* t_out_w= (const float*)d_in[7];
    const float* t_out_b= (const float*)d_in[8];
    const float* fus_w1 = (const float*)d_in[9];
    const float* fus_b1 = (const float*)d_in[10];
    const float* fus_w2 = (const float*)d_in[11];
    const float* fus_b2 = (const float*)d_in[12];
    const float* ffn_w1 = (const float*)d_in[13];
    const float* ffn_b1 = (const float*)d_in[14];
    const float* ffn_w2 = (const float*)d_in[15];
    const float* ffn_b2 = (const float*)d_in[16];
    const float* gn_g   = (const float*)d_in[17];
    const float* gn_b   = (const float*)d_in[18];
    const float* fn_g   = (const float*)d_in[19];
    const float* fn_b   = (const float*)d_in[20];
    float* out = (float*)d_out;
    float* ws  = (float*)d_ws;

    // workspace layout (floats); reuse dead buffers. Peak = 20,971,520 floats = 84 MB.
    float* qkv_g  = ws;                  // 8192*768
    float* qkv_l  = ws + 6291456;        // 8192*768
    float* attn_g = ws + 12582912;       // 8192*256
    float* attn_l = ws + 14680064;       // 8192*256
    float* comb   = ws + 16777216;       // 8192*512
    float* h1     = ws;                  // reuse qkv_g   (8192*512)
    float* xf     = ws + 6291456;        // reuse qkv_l   (8192*256)
    float* x2     = ws + 12582912;       // reuse attn_g  (8192*256)
    float* h2     = ws;                  // reuse h1      (8192*512)
    float* xff    = ws + 14680064;       // reuse attn_l  (8192*256)

    // 1-2: QKV projections (M=8192, N=768, K=256)
    gemm_nt<false><<<dim3(12, 64), 256, 0, stream>>>(x, g_in_w, g_in_b, qkv_g, 256, 768, 0);
    gemm_nt<false><<<dim3(12, 64), 256, 0, stream>>>(x, t_in_w, t_in_b, qkv_l, 256, 768, 0);
    // 3: global attention
    attn_global<<<dim3(256), 128, 0, stream>>>(qkv_g, attn_g);
    // 4: local attention
    attn_local<<<dim3(8192), 256, 0, stream>>>(qkv_l, attn_l);
    // 5-6: output projections into comb ([8192,512]: cols 0-255 global, 256-511 local)
    gemm_nt<false><<<dim3(4, 64), 256, 0, stream>>>(attn_g, g_out_w, g_out_b, comb, 256, 512, 0);
    gemm_nt<false><<<dim3(4, 64), 256, 0, stream>>>(attn_l, t_out_w, t_out_b, comb, 256, 512, 256);
    // 7: h1 = silu(comb @ fus_w1^T + fus_b1)   (N=512, K=512)
    gemm_nt<true><<<dim3(8, 64), 256, 0, stream>>>(comb, fus_w1, fus_b1, h1, 512, 512, 0);
    // 8: xf = h1 @ fus_w2^T + fus_b2           (N=256, K=512)
    gemm_nt<false><<<dim3(4, 64), 256, 0, stream>>>(h1, fus_w2, fus_b2, xf, 512, 256, 0);
    // 9: x2 = LN(x + xf)
    ln_residual<<<dim3(2048), 256, 0, stream>>>(x, xf, gn_g, gn_b, x2);
    // 10: h2 = silu(x2 @ ffn_w1^T + ffn_b1)    (N=512, K=256)
    gemm_nt<true><<<dim3(8, 64), 256, 0, stream>>>(x2, ffn_w1, ffn_b1, h2, 256, 512, 0);
    // 11: xff = h2 @ ffn_w2^T + ffn_b2         (N=256, K=512)
    gemm_nt<false><<<dim3(4, 64), 256, 0, stream>>>(h2, ffn_w2, ffn_b2, xff, 512, 256, 0);
    // 12: out = LN(x2 + xff)
    ln_residual<<<dim3(2048), 256, 0, stream>>>(x2, xff, fn_g, fn_b, out);
}

// Round 2
// 842.208 us; speedup vs baseline: 1.8551x; 1.8551x over previous
//
#include <hip/hip_runtime.h>

constexpr int Bb = 4;
constexpr int Ss = 2048;

// ---------------------------------------------------------------------------
// GEMM: C[m, coff+n] = act(sum_k A[m,k] * W[n,k] + bias[n])
// A: [M,K] row-major, W: [N,K] row-major (A @ W^T), C row stride ldc.
// BM=128, BN=64, BK=32; 256 threads; each thread 8x4 outputs.
// ---------------------------------------------------------------------------
template<bool SILU>
__global__ __launch_bounds__(256) void gemm_nt(
    const float* __restrict__ A, const float* __restrict__ W,
    const float* __restrict__ bias, float* __restrict__ C,
    int K, int ldc, int coff)
{
    constexpr int BM = 128, BN = 64, BK = 32;
    __shared__ float As[BK][BM + 4];
    __shared__ float Ws[BK][BN + 4];
    const int tid = threadIdx.x;
    const int tx = tid & 15;   // n-sub: n = tx*4
    const int ty = tid >> 4;   // m-sub: m = ty*8
    const int n0 = blockIdx.x * BN;
    const int m0 = blockIdx.y * BM;

    float acc[8][4];
#pragma unroll
    for (int i = 0; i < 8; i++)
#pragma unroll
        for (int j = 0; j < 4; j++) acc[i][j] = 0.f;

    for (int k0 = 0; k0 < K; k0 += BK) {
        __syncthreads();
#pragma unroll
        for (int i = 0; i < 4; i++) {
            int idx = i * 256 + tid;
            int row = idx >> 3, c4 = idx & 7;
            float4 v = *(const float4*)&A[(size_t)(m0 + row) * K + k0 + c4 * 4];
            As[c4 * 4 + 0][row] = v.x; As[c4 * 4 + 1][row] = v.y;
            As[c4 * 4 + 2][row] = v.z; As[c4 * 4 + 3][row] = v.w;
        }
#pragma unroll
        for (int i = 0; i < 2; i++) {
            int idx = i * 256 + tid;
            int row = idx >> 3, c4 = idx & 7;
            float4 v = *(const float4*)&W[(size_t)(n0 + row) * K + k0 + c4 * 4];
            Ws[c4 * 4 + 0][row] = v.x; Ws[c4 * 4 + 1][row] = v.y;
            Ws[c4 * 4 + 2][row] = v.z; Ws[c4 * 4 + 3][row] = v.w;
        }
        __syncthreads();
#pragma unroll
        for (int kk = 0; kk < BK; kk++) {
            float4 a0 = *(const float4*)&As[kk][ty * 8];
            float4 a1 = *(const float4*)&As[kk][ty * 8 + 4];
            float4 w0 = *(const float4*)&Ws[kk][tx * 4];
            float am[8] = {a0.x, a0.y, a0.z, a0.w, a1.x, a1.y, a1.z, a1.w};
            float wn[4] = {w0.x, w0.y, w0.z, w0.w};
#pragma unroll
            for (int i = 0; i < 8; i++)
#pragma unroll
                for (int j = 0; j < 4; j++)
                    acc[i][j] += am[i] * wn[j];
        }
    }

    const int n = n0 + tx * 4;
    float bz0 = bias[n + 0], bz1 = bias[n + 1], bz2 = bias[n + 2], bz3 = bias[n + 3];
#pragma unroll
    for (int i = 0; i < 8; i++) {
        float4 o;
        o.x = acc[i][0] + bz0; o.y = acc[i][1] + bz1;
        o.z = acc[i][2] + bz2; o.w = acc[i][3] + bz3;
        if (SILU) {
            o.x = o.x / (1.f + __expf(-o.x));
            o.y = o.y / (1.f + __expf(-o.y));
            o.z = o.z / (1.f + __expf(-o.z));
            o.w = o.w / (1.f + __expf(-o.w));
        }
        *(float4*)&C[(size_t)(m0 + ty * 8 + i) * ldc + coff + n] = o;
    }
}

// ---------------------------------------------------------------------------
// Global MHA, split-K flash partials. 8 heads, hd=32, S=2048.
// Grid: 2048 blocks = (b:4, h:8, qt:16, sp:4); block = 128 threads, 1 query
// per thread (q = qt*128 + tid). Each block processes keys [sp*512, sp*512+512)
// in 64-key LDS tiles and writes UNNORMALIZED partial o plus (m, l).
// Partial layout: o_part at opX + (gid)*32 where gid=((b*8+h)*2048+q), split s
// region base passed in; ml at ml + (s*65536+gid)*2.
// ---------------------------------------------------------------------------
__global__ __launch_bounds__(128, 4) void attn_global_part(
    const float* __restrict__ qkv,
    float* __restrict__ op012,      // splits 0..2, each 2097152 floats
    float* __restrict__ op3,        // split 3
    float* __restrict__ ml)         // [4][65536][2]
{
    const int tid = threadIdx.x;
    const int bid = blockIdx.x;
    const int sp = bid & 3;
    const int qt = (bid >> 2) & 15;
    const int h  = (bid >> 6) & 7;
    const int b  = bid >> 9;
    const float scale = 0.17677669529663687f; // 1/sqrt(32)

    __shared__ float kt[64][32];
    __shared__ float vt[64][32];

    const int q = qt * 128 + tid;

    float qr[32], o[32];
    {
        const float* pq = qkv + (size_t)(b * Ss + q) * 768 + h * 32;
#pragma unroll
        for (int i = 0; i < 8; i++) {
            float4 v = *(const float4*)&pq[i * 4];
            qr[i * 4 + 0] = v.x; qr[i * 4 + 1] = v.y;
            qr[i * 4 + 2] = v.z; qr[i * 4 + 3] = v.w;
        }
    }
#pragma unroll
    for (int d = 0; d < 32; d++) o[d] = 0.f;
    float m = -1e30f, l = 0.f;

    for (int t = 0; t < 8; t++) {
        __syncthreads();
#pragma unroll
        for (int i = 0; i < 4; i++) {
            int idx = i * 128 + tid;           // 0..511
            int row = idx >> 3, c4 = idx & 7;
            const float* kp = qkv + (size_t)(b * Ss + sp * 512 + t * 64 + row) * 768
                              + 256 + h * 32 + c4 * 4;
            *(float4*)&kt[row][c4 * 4] = *(const float4*)kp;
            *(float4*)&vt[row][c4 * 4] = *(const float4*)(kp + 256);
        }
        __syncthreads();
        for (int kk = 0; kk < 64; kk++) {
            float s = 0.f;
#pragma unroll
            for (int d4 = 0; d4 < 8; d4++) {
                float4 kv = *(const float4*)&kt[kk][d4 * 4];
                s += qr[d4 * 4 + 0] * kv.x + qr[d4 * 4 + 1] * kv.y
                   + qr[d4 * 4 + 2] * kv.z + qr[d4 * 4 + 3] * kv.w;
            }
            s *= scale;
            if (s > m) {
                float c = __expf(m - s);
                l *= c;
#pragma unroll
                for (int d = 0; d < 32; d++) o[d] *= c;
                m = s;
            }
            float p = __expf(s - m);
            l += p;
#pragma unroll
            for (int d4 = 0; d4 < 8; d4++) {
                float4 vv = *(const float4*)&vt[kk][d4 * 4];
                o[d4 * 4 + 0] += p * vv.x; o[d4 * 4 + 1] += p * vv.y;
                o[d4 * 4 + 2] += p * vv.z; o[d4 * 4 + 3] += p * vv.w;
            }
        }
    }

    const int gid = (b * 8 + h) * 2048 + q;
    float* opb = (sp < 3) ? (op012 + (size_t)sp * 2097152) : op3;
    float* po = opb + (size_t)gid * 32;
#pragma unroll
    for (int i = 0; i < 8; i++) {
        float4 v;
        v.x = o[i * 4 + 0]; v.y = o[i * 4 + 1];
        v.z = o[i * 4 + 2]; v.w = o[i * 4 + 3];
        *(float4*)&po[i * 4] = v;
    }
    float2 mlv; mlv.x = m; mlv.y = l;
    *(float2*)&ml[(size_t)(sp * 65536 + gid) * 2] = mlv;
}

// ---------------------------------------------------------------------------
// Combine 4 split partials -> attn_g [B,S,256].
// Thread t: gid = t>>3 (query id), dgrp = t&7 (float4 group of dims).
// ---------------------------------------------------------------------------
__global__ __launch_bounds__(256) void attn_combine(
    const float* __restrict__ op012, const float* __restrict__ op3,
    const float* __restrict__ ml, float* __restrict__ out)
{
    const int t = blockIdx.x * 256 + threadIdx.x;   // 0 .. 524287
    const int gid = t >> 3;
    const int dg = t & 7;
    const int b = gid >> 14;
    const int h = (gid >> 11) & 7;
    const int q = gid & 2047;

    float2 ml0 = *(const float2*)&ml[(size_t)(0 * 65536 + gid) * 2];
    float2 ml1 = *(const float2*)&ml[(size_t)(1 * 65536 + gid) * 2];
    float2 ml2 = *(const float2*)&ml[(size_t)(2 * 65536 + gid) * 2];
    float2 ml3 = *(const float2*)&ml[(size_t)(3 * 65536 + gid) * 2];
    float ms = fmaxf(fmaxf(ml0.x, ml1.x), fmaxf(ml2.x, ml3.x));
    float c0 = __expf(ml0.x - ms), c1 = __expf(ml1.x - ms);
    float c2 = __expf(ml2.x - ms), c3 = __expf(ml3.x - ms);
    float li = 1.f / (c0 * ml0.y + c1 * ml1.y + c2 * ml2.y + c3 * ml3.y);

    float4 o0 = *(const float4*)&op012[(size_t)(0 * 2097152) + (size_t)gid * 32 + dg * 4];
    float4 o1 = *(const float4*)&op012[(size_t)(1 * 2097152) + (size_t)gid * 32 + dg * 4];
    float4 o2 = *(const float4*)&op012[(size_t)(2 * 2097152) + (size_t)gid * 32 + dg * 4];
    float4 o3 = *(const float4*)&op3[(size_t)gid * 32 + dg * 4];
    float4 r;
    r.x = (c0 * o0.x + c1 * o1.x + c2 * o2.x + c3 * o3.x) * li;
    r.y = (c0 * o0.y + c1 * o1.y + c2 * o2.y + c3 * o3.y) * li;
    r.z = (c0 * o0.z + c1 * o1.z + c2 * o2.z + c3 * o3.z) * li;
    r.w = (c0 * o0.w + c1 * o1.w + c2 * o2.w + c3 * o3.w) * li;
    *(float4*)&out[(size_t)(b * Ss + q) * 256 + h * 32 + dg * 4] = r;
}

// ---------------------------------------------------------------------------
// Local windowed MHA: 4 heads, hd=64, window 5 (HALF=2). Wave per (b,s,h).
// ---------------------------------------------------------------------------
__global__ __launch_bounds__(256) void attn_local(
    const float* __restrict__ qkv, float* __restrict__ out)
{
    const int lane = threadIdx.x & 63;
    const int w = blockIdx.x * 4 + (threadIdx.x >> 6);
    const int b = w >> 13;
    const int rem = w & 8191;
    const int s = rem >> 2;
    const int h = rem & 3;

    const float q = qkv[(size_t)(b * Ss + s) * 768 + h * 64 + lane];
    float sc[5], vv[5];
#pragma unroll
    for (int j = 0; j < 5; j++) {
        int pos = s + j - 2;
        bool valid = (pos >= 0) && (pos < Ss);
        int cpos = valid ? pos : 0;
        const size_t rb = (size_t)(b * Ss + cpos) * 768;
        float kj = valid ? qkv[rb + 256 + h * 64 + lane] : 0.f;
        vv[j] = valid ? qkv[rb + 512 + h * 64 + lane] : 0.f;
        float p = q * kj;
#pragma unroll
        for (int off = 32; off > 0; off >>= 1) p += __shfl_xor(p, off, 64);
        sc[j] = valid ? p * 0.125f : -1e30f;
    }
    float m = sc[0];
#pragma unroll
    for (int j = 1; j < 5; j++) m = fmaxf(m, sc[j]);
    float l = 0.f, o = 0.f;
#pragma unroll
    for (int j = 0; j < 5; j++) {
        float p = __expf(sc[j] - m);
        l += p; o += p * vv[j];
    }
    out[(size_t)(b * Ss + s) * 256 + h * 64 + lane] = o / l;
}

// ---------------------------------------------------------------------------
// out = LayerNorm(a + r) * g + be over last dim (256). Wave per token.
// ---------------------------------------------------------------------------
__global__ __launch_bounds__(256) void ln_residual(
    const float* __restrict__ a, const float* __restrict__ r,
    const float* __restrict__ g, const float* __restrict__ be,
    float* __restrict__ out)
{
    const int lane = threadIdx.x & 63;
    const int tok = blockIdx.x * 4 + (threadIdx.x >> 6);
    float4 xa = ((const float4*)a)[(size_t)tok * 64 + lane];
    float4 xr = ((const float4*)r)[(size_t)tok * 64 + lane];
    float4 x;
    x.x = xa.x + xr.x; x.y = xa.y + xr.y; x.z = xa.z + xr.z; x.w = xa.w + xr.w;
    float sum = x.x + x.y + x.z + x.w;
#pragma unroll
    for (int off = 32; off > 0; off >>= 1) sum += __shfl_xor(sum, off, 64);
    float mu = sum * (1.f / 256.f);
    float4 c;
    c.x = x.x - mu; c.y = x.y - mu; c.z = x.z - mu; c.w = x.w - mu;
    float sq = c.x * c.x + c.y * c.y + c.z * c.z + c.w * c.w;
#pragma unroll
    for (int off = 32; off > 0; off >>= 1) sq += __shfl_xor(sq, off, 64);
    float rs = rsqrtf(sq * (1.f / 256.f) + 1e-5f);
    float4 gg = ((const float4*)g)[lane];
    float4 bb = ((const float4*)be)[lane];
    float4 o;
    o.x = c.x * rs * gg.x + bb.x; o.y = c.y * rs * gg.y + bb.y;
    o.z = c.z * rs * gg.z + bb.z; o.w = c.w * rs * gg.w + bb.w;
    ((float4*)out)[(size_t)tok * 64 + lane] = o;
}

// ---------------------------------------------------------------------------
extern "C" void kernel_launch(void* const* d_in, const int* in_sizes, int n_in,
                              void* d_out, int out_size, void* d_ws, size_t ws_size,
                              hipStream_t stream)
{
    const float* x      = (const float*)d_in[0];
    const float* g_in_w = (const float*)d_in[1];
    const float* g_in_b = (const float*)d_in[2];
    const float* g_out_w= (const float*)d_in[3];
    const float* g_out_b= (const float*)d_in[4];
    const float* t_in_w = (const float*)d_in[5];
    const float* t_in_b = (const float*)d_in[6];
    const float* t_out_w= (const float*)d_in[7];
    const float* t_out_b= (const float*)d_in[8];
    const float* fus_w1 = (const float*)d_in[9];
    const float* fus_b1 = (const float*)d_in[10];
    const float* fus_w2 = (const float*)d_in[11];
    const float* fus_b2 = (const float*)d_in[12];
    const float* ffn_w1 = (const float*)d_in[13];
    const float* ffn_b1 = (const float*)d_in[14];
    const float* ffn_w2 = (const float*)d_in[15];
    const float* ffn_b2 = (const float*)d_in[16];
    const float* gn_g   = (const float*)d_in[17];
    const float* gn_b   = (const float*)d_in[18];
    const float* fn_g   = (const float*)d_in[19];
    const float* fn_b   = (const float*)d_in[20];
    float* out = (float*)d_out;
    float* ws  = (float*)d_ws;

    // workspace layout (floats), peak 20,971,520 floats = 84 MB (known-safe):
    // [0,        6291456)  qkv_g          -> later h1 (4.2M) -> later h2
    // [6291456, 12582912)  qkv_l          -> later op splits 0-2 (6.29M) -> later xf
    // [12582912,14680064)  attn_g         -> later x2
    // [14680064,16777216)  attn_l         -> later xff
    // [16777216,20971520)  comb (4.19M); during attention: op split 3 (2.1M)
    //                      + ml (0.52M) at +2097152
    float* qkv_g  = ws;
    float* qkv_l  = ws + 6291456;
    float* attn_g = ws + 12582912;
    float* attn_l = ws + 14680064;
    float* comb   = ws + 16777216;
    float* op012  = ws + 6291456;        // reuses qkv_l after attn_local
    float* op3    = ws + 16777216;       // reuses comb (written later)
    float* ml     = ws + 16777216 + 2097152;
    float* h1     = ws;                  // reuses qkv_g
    float* xf     = ws + 6291456;        // reuses op012
    float* x2     = ws + 12582912;       // reuses attn_g
    float* h2     = ws;                  // reuses h1
    float* xff    = ws + 14680064;       // reuses attn_l

    // Local branch first (frees qkv_l for attention partials)
    gemm_nt<false><<<dim3(12, 64), 256, 0, stream>>>(x, t_in_w, t_in_b, qkv_l, 256, 768, 0);
    attn_local<<<dim3(8192), 256, 0, stream>>>(qkv_l, attn_l);
    // Global branch
    gemm_nt<false><<<dim3(12, 64), 256, 0, stream>>>(x, g_in_w, g_in_b, qkv_g, 256, 768, 0);
    attn_global_part<<<dim3(2048), 128, 0, stream>>>(qkv_g, op012, op3, ml);
    attn_combine<<<dim3(2048), 256, 0, stream>>>(op012, op3, ml, attn_g);
    // Output projections into comb ([8192,512]: cols 0-255 global, 256-511 local)
    gemm_nt<false><<<dim3(4, 64), 256, 0, stream>>>(attn_g, g_out_w, g_out_b, comb, 256, 512, 0);
    gemm_nt<false><<<dim3(4, 64), 256, 0, stream>>>(attn_l, t_out_w, t_out_b, comb, 256, 512, 256);
    // Fusion MLP
    gemm_nt<true><<<dim3(8, 64), 256, 0, stream>>>(comb, fus_w1, fus_b1, h1, 512, 512, 0);
    gemm_nt<false><<<dim3(4, 64), 256, 0, stream>>>(h1, fus_w2, fus_b2, xf, 512, 256, 0);
    ln_residual<<<dim3(2048), 256, 0, stream>>>(x, xf, gn_g, gn_b, x2);
    // FFN
    gemm_nt<true><<<dim3(8, 64), 256, 0, stream>>>(x2, ffn_w1, ffn_b1, h2, 256, 512, 0);
    gemm_nt<false><<<dim3(4, 64), 256, 0, stream>>>(h2, ffn_w2, ffn_b2, xff, 512, 256, 0);
    ln_residual<<<dim3(2048), 256, 0, stream>>>(x2, xff, fn_g, fn_b, out);
}

// Round 3
// 516.277 us; speedup vs baseline: 3.0262x; 1.6313x over previous
//
#include <hip/hip_runtime.h>

constexpr int Bb = 4;
constexpr int Ss = 2048;

typedef __bf16 bf16x8 __attribute__((ext_vector_type(8)));
typedef float  f32x4  __attribute__((ext_vector_type(4)));

// ---------------------------------------------------------------------------
// GEMM: C[m, coff+n] = act(sum_k A[m,k] * W[n,k] + bias[n])   (fp32, unchanged)
// ---------------------------------------------------------------------------
template<bool SILU>
__global__ __launch_bounds__(256) void gemm_nt(
    const float* __restrict__ A, const float* __restrict__ W,
    const float* __restrict__ bias, float* __restrict__ C,
    int K, int ldc, int coff)
{
    constexpr int BM = 128, BN = 64, BK = 32;
    __shared__ float As[BK][BM + 4];
    __shared__ float Ws[BK][BN + 4];
    const int tid = threadIdx.x;
    const int tx = tid & 15;
    const int ty = tid >> 4;
    const int n0 = blockIdx.x * BN;
    const int m0 = blockIdx.y * BM;

    float acc[8][4];
#pragma unroll
    for (int i = 0; i < 8; i++)
#pragma unroll
        for (int j = 0; j < 4; j++) acc[i][j] = 0.f;

    for (int k0 = 0; k0 < K; k0 += BK) {
        __syncthreads();
#pragma unroll
        for (int i = 0; i < 4; i++) {
            int idx = i * 256 + tid;
            int row = idx >> 3, c4 = idx & 7;
            float4 v = *(const float4*)&A[(size_t)(m0 + row) * K + k0 + c4 * 4];
            As[c4 * 4 + 0][row] = v.x; As[c4 * 4 + 1][row] = v.y;
            As[c4 * 4 + 2][row] = v.z; As[c4 * 4 + 3][row] = v.w;
        }
#pragma unroll
        for (int i = 0; i < 2; i++) {
            int idx = i * 256 + tid;
            int row = idx >> 3, c4 = idx & 7;
            float4 v = *(const float4*)&W[(size_t)(n0 + row) * K + k0 + c4 * 4];
            Ws[c4 * 4 + 0][row] = v.x; Ws[c4 * 4 + 1][row] = v.y;
            Ws[c4 * 4 + 2][row] = v.z; Ws[c4 * 4 + 3][row] = v.w;
        }
        __syncthreads();
#pragma unroll
        for (int kk = 0; kk < BK; kk++) {
            float4 a0 = *(const float4*)&As[kk][ty * 8];
            float4 a1 = *(const float4*)&As[kk][ty * 8 + 4];
            float4 w0 = *(const float4*)&Ws[kk][tx * 4];
            float am[8] = {a0.x, a0.y, a0.z, a0.w, a1.x, a1.y, a1.z, a1.w};
            float wn[4] = {w0.x, w0.y, w0.z, w0.w};
#pragma unroll
            for (int i = 0; i < 8; i++)
#pragma unroll
                for (int j = 0; j < 4; j++)
                    acc[i][j] += am[i] * wn[j];
        }
    }

    const int n = n0 + tx * 4;
    float bz0 = bias[n + 0], bz1 = bias[n + 1], bz2 = bias[n + 2], bz3 = bias[n + 3];
#pragma unroll
    for (int i = 0; i < 8; i++) {
        float4 o;
        o.x = acc[i][0] + bz0; o.y = acc[i][1] + bz1;
        o.z = acc[i][2] + bz2; o.w = acc[i][3] + bz3;
        if (SILU) {
            o.x = o.x / (1.f + __expf(-o.x));
            o.y = o.y / (1.f + __expf(-o.y));
            o.z = o.z / (1.f + __expf(-o.z));
            o.w = o.w / (1.f + __expf(-o.w));
        }
        *(float4*)&C[(size_t)(m0 + ty * 8 + i) * ldc + coff + n] = o;
    }
}

// ---------------------------------------------------------------------------
// Convert qkv_g fp32 [8192,768] -> bf16, scaling Q columns (0..255) by
// scale*log2e so attention probabilities are exp2(Q.K) directly.
// 8 elements/thread, 16B vector store.
// ---------------------------------------------------------------------------
__global__ __launch_bounds__(256) void qkv_to_bf16(
    const float* __restrict__ src, __bf16* __restrict__ dst)
{
    const int idx = blockIdx.x * 256 + threadIdx.x;   // 0 .. 786431
    const float c = 1.4426950408889634f * 0.17677669529663687f; // log2e/sqrt(32)
    const int col8 = idx % 96;
    const float s = (col8 < 32) ? c : 1.f;
    float4 a = *(const float4*)&src[(size_t)idx * 8];
    float4 b = *(const float4*)&src[(size_t)idx * 8 + 4];
    bf16x8 o;
    o[0] = (__bf16)(a.x * s); o[1] = (__bf16)(a.y * s);
    o[2] = (__bf16)(a.z * s); o[3] = (__bf16)(a.w * s);
    o[4] = (__bf16)(b.x * s); o[5] = (__bf16)(b.y * s);
    o[6] = (__bf16)(b.z * s); o[7] = (__bf16)(b.w * s);
    *(bf16x8*)&dst[(size_t)idx * 8] = o;
}

// ---------------------------------------------------------------------------
// Global MHA via MFMA 16x16x32 bf16. 8 heads, hd=32, S=2048, no-max softmax
// (scores are O(0.5); exp2 with scale folded into Q).
// Block: 256 thr = 4 waves, 64 queries (16/wave). Grid: 1024 = (b:4,h:8,qc:32).
// Per 64-key chunk: K staged [key][dim] stride 40, V transposed [dim][key]
// stride 72. Per 32 keys: 2 QK MFMAs -> exp2 -> P via per-wave LDS (C-layout
// -> A-layout) -> 2 PV MFMAs. l per-lane, quad-reduced at end.
// ---------------------------------------------------------------------------
__global__ __launch_bounds__(256) void attn_global_mfma(
    const __bf16* __restrict__ qkv, float* __restrict__ out)
{
    __shared__ __bf16 Kl[64 * 40];
    __shared__ __bf16 Vt[32 * 72];
    __shared__ __bf16 Pl[4][16 * 40];

    const int t = threadIdx.x;
    const int bid = blockIdx.x;
    const int qc = bid & 31;
    const int h  = (bid >> 5) & 7;
    const int b  = bid >> 8;
    const int bS = b * Ss;
    const int q0 = qc * 64;

    const int lane = t & 63;
    const int wv = t >> 6;
    const int qrow = lane & 15;
    const int quad = lane >> 4;

    // Q fragment: A[m=lane&15][k=quad*8+j], pre-scaled bf16
    const bf16x8 qf = *(const bf16x8*)(qkv +
        (size_t)(bS + q0 + wv * 16 + qrow) * 768 + h * 32 + quad * 8);

    f32x4 o0 = {0.f, 0.f, 0.f, 0.f};
    f32x4 o1 = {0.f, 0.f, 0.f, 0.f};
    float l[4] = {0.f, 0.f, 0.f, 0.f};
    const f32x4 z = {0.f, 0.f, 0.f, 0.f};

    for (int kc = 0; kc < 32; kc++) {
        __syncthreads();
        {   // stage K: [key][dim], 16B per thread
            int key = t >> 2, dg = t & 3;
            const __bf16* src = qkv + (size_t)(bS + kc * 64 + key) * 768 + 256 + h * 32 + dg * 8;
            *(bf16x8*)&Kl[key * 40 + dg * 8] = *(const bf16x8*)src;
        }
        {   // stage V transposed: [dim][key]
            int key = t & 63, dg = t >> 6;
            const __bf16* src = qkv + (size_t)(bS + kc * 64 + key) * 768 + 512 + h * 32 + dg * 8;
            bf16x8 v = *(const bf16x8*)src;
#pragma unroll
            for (int i = 0; i < 8; i++) Vt[(dg * 8 + i) * 72 + key] = v[i];
        }
        __syncthreads();

#pragma unroll
        for (int half = 0; half < 2; half++) {
            const int k0 = half * 32;
            // B-frags for QK: lane holds K[k0 + (lane&15) (+16)][quad*8..+7]
            bf16x8 kf0 = *(const bf16x8*)&Kl[(k0 + qrow) * 40 + quad * 8];
            bf16x8 kf1 = *(const bf16x8*)&Kl[(k0 + 16 + qrow) * 40 + quad * 8];
            f32x4 s0 = __builtin_amdgcn_mfma_f32_16x16x32_bf16(qf, kf0, z, 0, 0, 0);
            f32x4 s1 = __builtin_amdgcn_mfma_f32_16x16x32_bf16(qf, kf1, z, 0, 0, 0);
            // p = exp2(s); accumulate l; write P (C-layout -> LDS)
#pragma unroll
            for (int r = 0; r < 4; r++) {
                float p0 = exp2f(s0[r]);
                float p1 = exp2f(s1[r]);
                l[r] += p0 + p1;
                Pl[wv][(quad * 4 + r) * 40 + qrow]      = (__bf16)p0;
                Pl[wv][(quad * 4 + r) * 40 + 16 + qrow] = (__bf16)p1;
            }
            // A-frag of P: P[q=lane&15][k=quad*8+j]  (same-wave LDS dependency)
            bf16x8 pf = *(const bf16x8*)&Pl[wv][qrow * 40 + quad * 8];
            // B-frags of V: V[k0+quad*8+j][d0 + lane&15] from Vt
            bf16x8 vf0 = *(const bf16x8*)&Vt[qrow * 72 + k0 + quad * 8];
            bf16x8 vf1 = *(const bf16x8*)&Vt[(16 + qrow) * 72 + k0 + quad * 8];
            o0 = __builtin_amdgcn_mfma_f32_16x16x32_bf16(pf, vf0, o0, 0, 0, 0);
            o1 = __builtin_amdgcn_mfma_f32_16x16x32_bf16(pf, vf1, o1, 0, 0, 0);
        }
    }

    // reduce l across the 16 lanes of each quad (cols of the score tile)
#pragma unroll
    for (int r = 0; r < 4; r++) {
#pragma unroll
        for (int off = 1; off < 16; off <<= 1)
            l[r] += __shfl_xor(l[r], off, 64);
    }
    // write O: row = q0 + wv*16 + quad*4 + r, cols h*32 + qrow (+16)
#pragma unroll
    for (int r = 0; r < 4; r++) {
        float iv = 1.f / l[r];
        const int row = q0 + wv * 16 + quad * 4 + r;
        float* po = out + (size_t)(bS + row) * 256 + h * 32;
        po[qrow]      = o0[r] * iv;
        po[16 + qrow] = o1[r] * iv;
    }
}

// ---------------------------------------------------------------------------
// Local windowed MHA: 4 heads, hd=64, window 5. Wave per (b,s,h). (unchanged)
// ---------------------------------------------------------------------------
__global__ __launch_bounds__(256) void attn_local(
    const float* __restrict__ qkv, float* __restrict__ out)
{
    const int lane = threadIdx.x & 63;
    const int w = blockIdx.x * 4 + (threadIdx.x >> 6);
    const int b = w >> 13;
    const int rem = w & 8191;
    const int s = rem >> 2;
    const int h = rem & 3;

    const float q = qkv[(size_t)(b * Ss + s) * 768 + h * 64 + lane];
    float sc[5], vv[5];
#pragma unroll
    for (int j = 0; j < 5; j++) {
        int pos = s + j - 2;
        bool valid = (pos >= 0) && (pos < Ss);
        int cpos = valid ? pos : 0;
        const size_t rb = (size_t)(b * Ss + cpos) * 768;
        float kj = valid ? qkv[rb + 256 + h * 64 + lane] : 0.f;
        vv[j] = valid ? qkv[rb + 512 + h * 64 + lane] : 0.f;
        float p = q * kj;
#pragma unroll
        for (int off = 32; off > 0; off >>= 1) p += __shfl_xor(p, off, 64);
        sc[j] = valid ? p * 0.125f : -1e30f;
    }
    float m = sc[0];
#pragma unroll
    for (int j = 1; j < 5; j++) m = fmaxf(m, sc[j]);
    float l = 0.f, o = 0.f;
#pragma unroll
    for (int j = 0; j < 5; j++) {
        float p = __expf(sc[j] - m);
        l += p; o += p * vv[j];
    }
    out[(size_t)(b * Ss + s) * 256 + h * 64 + lane] = o / l;
}

// ---------------------------------------------------------------------------
// out = LayerNorm(a + r) * g + be over last dim (256). Wave per token.
// ---------------------------------------------------------------------------
__global__ __launch_bounds__(256) void ln_residual(
    const float* __restrict__ a, const float* __restrict__ r,
    const float* __restrict__ g, const float* __restrict__ be,
    float* __restrict__ out)
{
    const int lane = threadIdx.x & 63;
    const int tok = blockIdx.x * 4 + (threadIdx.x >> 6);
    float4 xa = ((const float4*)a)[(size_t)tok * 64 + lane];
    float4 xr = ((const float4*)r)[(size_t)tok * 64 + lane];
    float4 x;
    x.x = xa.x + xr.x; x.y = xa.y + xr.y; x.z = xa.z + xr.z; x.w = xa.w + xr.w;
    float sum = x.x + x.y + x.z + x.w;
#pragma unroll
    for (int off = 32; off > 0; off >>= 1) sum += __shfl_xor(sum, off, 64);
    float mu = sum * (1.f / 256.f);
    float4 c;
    c.x = x.x - mu; c.y = x.y - mu; c.z = x.z - mu; c.w = x.w - mu;
    float sq = c.x * c.x + c.y * c.y + c.z * c.z + c.w * c.w;
#pragma unroll
    for (int off = 32; off > 0; off >>= 1) sq += __shfl_xor(sq, off, 64);
    float rs = rsqrtf(sq * (1.f / 256.f) + 1e-5f);
    float4 gg = ((const float4*)g)[lane];
    float4 bb = ((const float4*)be)[lane];
    float4 o;
    o.x = c.x * rs * gg.x + bb.x; o.y = c.y * rs * gg.y + bb.y;
    o.z = c.z * rs * gg.z + bb.z; o.w = c.w * rs * gg.w + bb.w;
    ((float4*)out)[(size_t)tok * 64 + lane] = o;
}

// ---------------------------------------------------------------------------
extern "C" void kernel_launch(void* const* d_in, const int* in_sizes, int n_in,
                              void* d_out, int out_size, void* d_ws, size_t ws_size,
                              hipStream_t stream)
{
    const float* x      = (const float*)d_in[0];
    const float* g_in_w = (const float*)d_in[1];
    const float* g_in_b = (const float*)d_in[2];
    const float* g_out_w= (const float*)d_in[3];
    const float* g_out_b= (const float*)d_in[4];
    const float* t_in_w = (const float*)d_in[5];
    const float* t_in_b = (const float*)d_in[6];
    const float* t_out_w= (const float*)d_in[7];
    const float* t_out_b= (const float*)d_in[8];
    const float* fus_w1 = (const float*)d_in[9];
    const float* fus_b1 = (const float*)d_in[10];
    const float* fus_w2 = (const float*)d_in[11];
    const float* fus_b2 = (const float*)d_in[12];
    const float* ffn_w1 = (const float*)d_in[13];
    const float* ffn_b1 = (const float*)d_in[14];
    const float* ffn_w2 = (const float*)d_in[15];
    const float* ffn_b2 = (const float*)d_in[16];
    const float* gn_g   = (const float*)d_in[17];
    const float* gn_b   = (const float*)d_in[18];
    const float* fn_g   = (const float*)d_in[19];
    const float* fn_b   = (const float*)d_in[20];
    float* out = (float*)d_out;
    float* ws  = (float*)d_ws;

    // workspace layout (floats), peak 20,971,520 floats = 84 MB (known-safe):
    // [0,        6291456)  qkv_g fp32      -> later h1 -> h2
    // [6291456, 12582912)  qkv_l fp32      -> later qkvb bf16 (3.15M slots) -> xf
    // [12582912,14680064)  attn_g          -> later x2
    // [14680064,16777216)  attn_l          -> later xff
    // [16777216,20971520)  comb
    float* qkv_g  = ws;
    float* qkv_l  = ws + 6291456;
    __bf16* qkvb  = (__bf16*)(ws + 6291456);   // reuses qkv_l region after attn_local
    float* attn_g = ws + 12582912;
    float* attn_l = ws + 14680064;
    float* comb   = ws + 16777216;
    float* h1     = ws;
    float* xf     = ws + 6291456;
    float* x2     = ws + 12582912;
    float* h2     = ws;
    float* xff    = ws + 14680064;

    // Local branch first (frees qkv_l region for the bf16 QKV)
    gemm_nt<false><<<dim3(12, 64), 256, 0, stream>>>(x, t_in_w, t_in_b, qkv_l, 256, 768, 0);
    attn_local<<<dim3(8192), 256, 0, stream>>>(qkv_l, attn_l);
    // Global branch: fp32 QKV -> bf16 (Q pre-scaled) -> MFMA flash attention
    gemm_nt<false><<<dim3(12, 64), 256, 0, stream>>>(x, g_in_w, g_in_b, qkv_g, 256, 768, 0);
    qkv_to_bf16<<<dim3(3072), 256, 0, stream>>>(qkv_g, qkvb);
    attn_global_mfma<<<dim3(1024), 256, 0, stream>>>(qkvb, attn_g);
    // Output projections into comb ([8192,512]: cols 0-255 global, 256-511 local)
    gemm_nt<false><<<dim3(4, 64), 256, 0, stream>>>(attn_g, g_out_w, g_out_b, comb, 256, 512, 0);
    gemm_nt<false><<<dim3(4, 64), 256, 0, stream>>>(attn_l, t_out_w, t_out_b, comb, 256, 512, 256);
    // Fusion MLP
    gemm_nt<true><<<dim3(8, 64), 256, 0, stream>>>(comb, fus_w1, fus_b1, h1, 512, 512, 0);
    gemm_nt<false><<<dim3(4, 64), 256, 0, stream>>>(h1, fus_w2, fus_b2, xf, 512, 256, 0);
    ln_residual<<<dim3(2048), 256, 0, stream>>>(x, xf, gn_g, gn_b, x2);
    // FFN
    gemm_nt<true><<<dim3(8, 64), 256, 0, stream>>>(x2, ffn_w1, ffn_b1, h2, 256, 512, 0);
    gemm_nt<false><<<dim3(4, 64), 256, 0, stream>>>(h2, ffn_w2, ffn_b2, xff, 512, 256, 0);
    ln_residual<<<dim3(2048), 256, 0, stream>>>(x2, xff, fn_g, fn_b, out);
}

// Round 4
// 281.332 us; speedup vs baseline: 5.5535x; 1.8351x over previous
//
#include <hip/hip_runtime.h>

constexpr int Bb = 4;
constexpr int Ss = 2048;

typedef __bf16 bf16x8 __attribute__((ext_vector_type(8)));
typedef __bf16 bf16x4 __attribute__((ext_vector_type(4)));
typedef float  f32x4  __attribute__((ext_vector_type(4)));

// ---------------------------------------------------------------------------
// convert_all: fp32 -> bf16 for x and the 8 weight matrices, one launch.
// Each block = 2048 elements (256 thr x 8). Entry found by scanning starts.
// ---------------------------------------------------------------------------
struct CvtArgs {
    const float* src[9];
    __bf16* dst[9];
    int start[10];
};

__global__ __launch_bounds__(256) void convert_all(CvtArgs a)
{
    int e = 0;
    const int bid = blockIdx.x;
#pragma unroll
    for (int i = 0; i < 8; i++) if (bid >= a.start[i + 1]) e = i + 1;
    const int idx = (bid - a.start[e]) * 256 + threadIdx.x;
    const float* s = a.src[e];
    float4 v0 = *(const float4*)&s[(size_t)idx * 8];
    float4 v1 = *(const float4*)&s[(size_t)idx * 8 + 4];
    bf16x8 o;
    o[0] = (__bf16)v0.x; o[1] = (__bf16)v0.y; o[2] = (__bf16)v0.z; o[3] = (__bf16)v0.w;
    o[4] = (__bf16)v1.x; o[5] = (__bf16)v1.y; o[6] = (__bf16)v1.z; o[7] = (__bf16)v1.w;
    *(bf16x8*)&a.dst[e][(size_t)idx * 8] = o;
}

// ---------------------------------------------------------------------------
// bf16 MFMA GEMM: C[m, coff+n] = act(sum_k A[m,k]*W[n,k] + bias[n])
// A [M,K] bf16 row-major, W [N,K] bf16 row-major. BM=BN=128, BK=64.
// 256 thr = 4 waves (2x2 of 64x64), each wave 4x4 mfma_f32_16x16x32_bf16.
// LDS row stride 72 (8-way b128 aliasing = the 8-cycle floor).
// ---------------------------------------------------------------------------
template<bool SILU, bool OUT_BF16>
__global__ __launch_bounds__(256) void gemm_bf16(
    const __bf16* __restrict__ A, const __bf16* __restrict__ W,
    const float* __restrict__ bias, void* __restrict__ C,
    int K, int ldc, int coff)
{
    __shared__ __bf16 As[128 * 72];
    __shared__ __bf16 Ws[128 * 72];
    const int tid = threadIdx.x;
    const int lane = tid & 63;
    const int wv = tid >> 6;
    const int wm = (wv >> 1) * 64;
    const int wn = (wv & 1) * 64;
    const int qrow = lane & 15;
    const int quad = lane >> 4;
    const int n0 = blockIdx.x * 128;
    const int m0 = blockIdx.y * 128;

    f32x4 acc[4][4];
#pragma unroll
    for (int i = 0; i < 4; i++)
#pragma unroll
        for (int j = 0; j < 4; j++) acc[i][j] = {0.f, 0.f, 0.f, 0.f};

    const int srow = tid >> 3;       // staging: row 0..127 (pairs of rows per 16 thr)
    const int scg  = tid & 7;        // 16B chunk 0..7 within the 64-k row

    for (int k0 = 0; k0 < K; k0 += 64) {
        __syncthreads();
        // stage A: 128 rows x 64 k x 2B = 8 chunks/row, 4 chunks per thread
#pragma unroll
        for (int i = 0; i < 4; i++) {
            int row = srow + (i >> 1) * 64;              // i=0,1 -> +0 ; i=2,3 -> +64
            int cg  = scg + (i & 1) * 8;                 // hmm: cover 8 chunks via 2 steps
            // simpler exact mapping: chunk id c = i*256 + tid; row=c>>3, cg=c&7
            int c = i * 256 + tid;
            row = c >> 3; cg = c & 7;
            *(bf16x8*)&As[row * 72 + cg * 8] =
                *(const bf16x8*)&A[(size_t)(m0 + row) * K + k0 + cg * 8];
        }
#pragma unroll
        for (int i = 0; i < 4; i++) {
            int c = i * 256 + tid;
            int row = c >> 3, cg = c & 7;
            *(bf16x8*)&Ws[row * 72 + cg * 8] =
                *(const bf16x8*)&W[(size_t)(n0 + row) * K + k0 + cg * 8];
        }
        __syncthreads();
#pragma unroll
        for (int ksub = 0; ksub < 2; ksub++) {
            bf16x8 af[4], bf[4];
#pragma unroll
            for (int mi = 0; mi < 4; mi++)
                af[mi] = *(const bf16x8*)&As[(wm + mi * 16 + qrow) * 72 + ksub * 32 + quad * 8];
#pragma unroll
            for (int ni = 0; ni < 4; ni++)
                bf[ni] = *(const bf16x8*)&Ws[(wn + ni * 16 + qrow) * 72 + ksub * 32 + quad * 8];
#pragma unroll
            for (int mi = 0; mi < 4; mi++)
#pragma unroll
                for (int ni = 0; ni < 4; ni++)
                    acc[mi][ni] = __builtin_amdgcn_mfma_f32_16x16x32_bf16(
                        af[mi], bf[ni], acc[mi][ni], 0, 0, 0);
        }
    }

    float bz[4];
#pragma unroll
    for (int ni = 0; ni < 4; ni++) bz[ni] = bias[n0 + wn + ni * 16 + qrow];

#pragma unroll
    for (int mi = 0; mi < 4; mi++) {
#pragma unroll
        for (int r = 0; r < 4; r++) {
            const int row = m0 + wm + mi * 16 + quad * 4 + r;
#pragma unroll
            for (int ni = 0; ni < 4; ni++) {
                float v = acc[mi][ni][r] + bz[ni];
                if (SILU) v = v / (1.f + __expf(-v));
                const int col = coff + n0 + wn + ni * 16 + qrow;
                if (OUT_BF16)
                    ((__bf16*)C)[(size_t)row * ldc + col] = (__bf16)v;
                else
                    ((float*)C)[(size_t)row * ldc + col] = v;
            }
        }
    }
}

// ---------------------------------------------------------------------------
// Global MHA via MFMA 16x16x32 bf16. 8 heads, hd=32, S=2048, no-max softmax.
// qkv bf16 [B*S,768] unscaled; Q scaled by log2e/sqrt(32) at frag load.
// Block: 4 waves, 64 queries. Grid: 1024 = (b:4,h:8,qc:32). Output bf16.
// ---------------------------------------------------------------------------
__global__ __launch_bounds__(256) void attn_global_mfma(
    const __bf16* __restrict__ qkv, __bf16* __restrict__ out)
{
    __shared__ __bf16 Kl[64 * 40];
    __shared__ __bf16 Vt[32 * 72];
    __shared__ __bf16 Pl[4][16 * 40];

    const int t = threadIdx.x;
    const int bid = blockIdx.x;
    const int qc = bid & 31;
    const int h  = (bid >> 5) & 7;
    const int b  = bid >> 8;
    const int bS = b * Ss;
    const int q0 = qc * 64;

    const int lane = t & 63;
    const int wv = t >> 6;
    const int qrow = lane & 15;
    const int quad = lane >> 4;
    const float cQ = 1.4426950408889634f * 0.17677669529663687f;

    bf16x8 qf;
    {
        bf16x8 qraw = *(const bf16x8*)(qkv +
            (size_t)(bS + q0 + wv * 16 + qrow) * 768 + h * 32 + quad * 8);
#pragma unroll
        for (int i = 0; i < 8; i++) qf[i] = (__bf16)((float)qraw[i] * cQ);
    }

    f32x4 o0 = {0.f, 0.f, 0.f, 0.f};
    f32x4 o1 = {0.f, 0.f, 0.f, 0.f};
    float l[4] = {0.f, 0.f, 0.f, 0.f};
    const f32x4 z = {0.f, 0.f, 0.f, 0.f};

    for (int kc = 0; kc < 32; kc++) {
        __syncthreads();
        {   // stage K: [key][dim]
            int key = t >> 2, dg = t & 3;
            const __bf16* src = qkv + (size_t)(bS + kc * 64 + key) * 768 + 256 + h * 32 + dg * 8;
            *(bf16x8*)&Kl[key * 40 + dg * 8] = *(const bf16x8*)src;
        }
        {   // stage V transposed: [dim][key]
            int key = t & 63, dg = t >> 6;
            const __bf16* src = qkv + (size_t)(bS + kc * 64 + key) * 768 + 512 + h * 32 + dg * 8;
            bf16x8 v = *(const bf16x8*)src;
#pragma unroll
            for (int i = 0; i < 8; i++) Vt[(dg * 8 + i) * 72 + key] = v[i];
        }
        __syncthreads();

#pragma unroll
        for (int half = 0; half < 2; half++) {
            const int k0 = half * 32;
            bf16x8 kf0 = *(const bf16x8*)&Kl[(k0 + qrow) * 40 + quad * 8];
            bf16x8 kf1 = *(const bf16x8*)&Kl[(k0 + 16 + qrow) * 40 + quad * 8];
            f32x4 s0 = __builtin_amdgcn_mfma_f32_16x16x32_bf16(qf, kf0, z, 0, 0, 0);
            f32x4 s1 = __builtin_amdgcn_mfma_f32_16x16x32_bf16(qf, kf1, z, 0, 0, 0);
#pragma unroll
            for (int r = 0; r < 4; r++) {
                float p0 = exp2f(s0[r]);
                float p1 = exp2f(s1[r]);
                l[r] += p0 + p1;
                Pl[wv][(quad * 4 + r) * 40 + qrow]      = (__bf16)p0;
                Pl[wv][(quad * 4 + r) * 40 + 16 + qrow] = (__bf16)p1;
            }
            bf16x8 pf = *(const bf16x8*)&Pl[wv][qrow * 40 + quad * 8];
            bf16x8 vf0 = *(const bf16x8*)&Vt[qrow * 72 + k0 + quad * 8];
            bf16x8 vf1 = *(const bf16x8*)&Vt[(16 + qrow) * 72 + k0 + quad * 8];
            o0 = __builtin_amdgcn_mfma_f32_16x16x32_bf16(pf, vf0, o0, 0, 0, 0);
            o1 = __builtin_amdgcn_mfma_f32_16x16x32_bf16(pf, vf1, o1, 0, 0, 0);
        }
    }

#pragma unroll
    for (int r = 0; r < 4; r++) {
#pragma unroll
        for (int off = 1; off < 16; off <<= 1)
            l[r] += __shfl_xor(l[r], off, 64);
    }
#pragma unroll
    for (int r = 0; r < 4; r++) {
        float iv = 1.f / l[r];
        const int row = q0 + wv * 16 + quad * 4 + r;
        __bf16* po = out + (size_t)(bS + row) * 256 + h * 32;
        po[qrow]      = (__bf16)(o0[r] * iv);
        po[16 + qrow] = (__bf16)(o1[r] * iv);
    }
}

// ---------------------------------------------------------------------------
// Local windowed MHA: 4 heads, hd=64, window 5. Wave per (b,s,h). bf16 I/O.
// ---------------------------------------------------------------------------
__global__ __launch_bounds__(256) void attn_local(
    const __bf16* __restrict__ qkv, __bf16* __restrict__ out)
{
    const int lane = threadIdx.x & 63;
    const int w = blockIdx.x * 4 + (threadIdx.x >> 6);
    const int b = w >> 13;
    const int rem = w & 8191;
    const int s = rem >> 2;
    const int h = rem & 3;

    const float q = (float)qkv[(size_t)(b * Ss + s) * 768 + h * 64 + lane];
    float sc[5], vv[5];
#pragma unroll
    for (int j = 0; j < 5; j++) {
        int pos = s + j - 2;
        bool valid = (pos >= 0) && (pos < Ss);
        int cpos = valid ? pos : 0;
        const size_t rb = (size_t)(b * Ss + cpos) * 768;
        float kj = valid ? (float)qkv[rb + 256 + h * 64 + lane] : 0.f;
        vv[j] = valid ? (float)qkv[rb + 512 + h * 64 + lane] : 0.f;
        float p = q * kj;
#pragma unroll
        for (int off = 32; off > 0; off >>= 1) p += __shfl_xor(p, off, 64);
        sc[j] = valid ? p * 0.125f : -1e30f;
    }
    float m = sc[0];
#pragma unroll
    for (int j = 1; j < 5; j++) m = fmaxf(m, sc[j]);
    float l = 0.f, o = 0.f;
#pragma unroll
    for (int j = 0; j < 5; j++) {
        float p = __expf(sc[j] - m);
        l += p; o += p * vv[j];
    }
    out[(size_t)(b * Ss + s) * 256 + h * 64 + lane] = (__bf16)(o / l);
}

// ---------------------------------------------------------------------------
// out = LayerNorm(a + r) * g + be over last dim (256). Wave per token.
// Writes fp32 always; optionally bf16 copy (ob != nullptr).
// ---------------------------------------------------------------------------
__global__ __launch_bounds__(256) void ln_residual(
    const float* __restrict__ a, const float* __restrict__ r,
    const float* __restrict__ g, const float* __restrict__ be,
    float* __restrict__ out, __bf16* __restrict__ ob)
{
    const int lane = threadIdx.x & 63;
    const int tok = blockIdx.x * 4 + (threadIdx.x >> 6);
    float4 xa = ((const float4*)a)[(size_t)tok * 64 + lane];
    float4 xr = ((const float4*)r)[(size_t)tok * 64 + lane];
    float4 x;
    x.x = xa.x + xr.x; x.y = xa.y + xr.y; x.z = xa.z + xr.z; x.w = xa.w + xr.w;
    float sum = x.x + x.y + x.z + x.w;
#pragma unroll
    for (int off = 32; off > 0; off >>= 1) sum += __shfl_xor(sum, off, 64);
    float mu = sum * (1.f / 256.f);
    float4 c;
    c.x = x.x - mu; c.y = x.y - mu; c.z = x.z - mu; c.w = x.w - mu;
    float sq = c.x * c.x + c.y * c.y + c.z * c.z + c.w * c.w;
#pragma unroll
    for (int off = 32; off > 0; off >>= 1) sq += __shfl_xor(sq, off, 64);
    float rs = rsqrtf(sq * (1.f / 256.f) + 1e-5f);
    float4 gg = ((const float4*)g)[lane];
    float4 bb = ((const float4*)be)[lane];
    float4 o;
    o.x = c.x * rs * gg.x + bb.x; o.y = c.y * rs * gg.y + bb.y;
    o.z = c.z * rs * gg.z + bb.z; o.w = c.w * rs * gg.w + bb.w;
    ((float4*)out)[(size_t)tok * 64 + lane] = o;
    if (ob) {
        bf16x4 h;
        h[0] = (__bf16)o.x; h[1] = (__bf16)o.y; h[2] = (__bf16)o.z; h[3] = (__bf16)o.w;
        *(bf16x4*)&ob[(size_t)tok * 256 + lane * 4] = h;
    }
}

// ---------------------------------------------------------------------------
extern "C" void kernel_launch(void* const* d_in, const int* in_sizes, int n_in,
                              void* d_out, int out_size, void* d_ws, size_t ws_size,
                              hipStream_t stream)
{
    const float* x      = (const float*)d_in[0];
    const float* g_in_w = (const float*)d_in[1];
    const float* g_in_b = (const float*)d_in[2];
    const float* g_out_w= (const float*)d_in[3];
    const float* g_out_b= (const float*)d_in[4];
    const float* t_in_w = (const float*)d_in[5];
    const float* t_in_b = (const float*)d_in[6];
    const float* t_out_w= (const float*)d_in[7];
    const float* t_out_b= (const float*)d_in[8];
    const float* fus_w1 = (const float*)d_in[9];
    const float* fus_b1 = (const float*)d_in[10];
    const float* fus_w2 = (const float*)d_in[11];
    const float* fus_b2 = (const float*)d_in[12];
    const float* ffn_w1 = (const float*)d_in[13];
    const float* ffn_b1 = (const float*)d_in[14];
    const float* ffn_w2 = (const float*)d_in[15];
    const float* ffn_b2 = (const float*)d_in[16];
    const float* gn_g   = (const float*)d_in[17];
    const float* gn_b   = (const float*)d_in[18];
    const float* fn_g   = (const float*)d_in[19];
    const float* fn_b   = (const float*)d_in[20];
    float* out = (float*)d_out;
    float* ws  = (float*)d_ws;

    // ws layout in f32 slots (peak 19,529,728 slots = 78.1 MB, ws >= 84 MB known):
    __bf16* xb     = (__bf16*)(ws);                 // 8192x256
    __bf16* wb     = (__bf16*)(ws + 1048576);       // all weights, 1,179,648 bf16
    __bf16* qkvg_b = (__bf16*)(ws + 1703936);       // 8192x768
    __bf16* qkvl_b = (__bf16*)(ws + 4849664);       // 8192x768
    __bf16* attng  = (__bf16*)(ws + 7995392);       // 8192x256
    __bf16* attnl  = (__bf16*)(ws + 9043968);       // 8192x256
    __bf16* comb   = (__bf16*)(ws + 10092544);      // 8192x512
    __bf16* h1     = (__bf16*)(ws + 12189696);      // 8192x512
    float*  xf     = ws + 14286848;                 // 8192x256 fp32
    float*  x2     = ws + 16384000;                 // 8192x256 fp32
    __bf16* x2b    = (__bf16*)(ws + 18481152);      // 8192x256
    __bf16* h2     = (__bf16*)(ws + 12189696);      // reuse h1
    float*  xff    = ws + 14286848;                 // reuse xf

    __bf16* w_gin  = wb;
    __bf16* w_tin  = wb + 196608;
    __bf16* w_gout = wb + 393216;
    __bf16* w_tout = wb + 458752;
    __bf16* w_f1   = wb + 524288;
    __bf16* w_f2   = wb + 786432;
    __bf16* w_n1   = wb + 917504;
    __bf16* w_n2   = wb + 1048576;

    CvtArgs ca;
    ca.src[0] = x;      ca.dst[0] = xb;
    ca.src[1] = g_in_w; ca.dst[1] = w_gin;
    ca.src[2] = t_in_w; ca.dst[2] = w_tin;
    ca.src[3] = g_out_w;ca.dst[3] = w_gout;
    ca.src[4] = t_out_w;ca.dst[4] = w_tout;
    ca.src[5] = fus_w1; ca.dst[5] = w_f1;
    ca.src[6] = fus_w2; ca.dst[6] = w_f2;
    ca.src[7] = ffn_w1; ca.dst[7] = w_n1;
    ca.src[8] = ffn_w2; ca.dst[8] = w_n2;
    int st[10] = {0, 1024, 1120, 1216, 1248, 1280, 1408, 1472, 1536, 1600};
    for (int i = 0; i < 10; i++) ca.start[i] = st[i];

    convert_all<<<dim3(1600), 256, 0, stream>>>(ca);

    // QKV projections (M=8192, N=768, K=256), bf16 out
    gemm_bf16<false, true><<<dim3(6, 64), 256, 0, stream>>>(xb, w_tin, t_in_b, qkvl_b, 256, 768, 0);
    attn_local<<<dim3(8192), 256, 0, stream>>>(qkvl_b, attnl);
    gemm_bf16<false, true><<<dim3(6, 64), 256, 0, stream>>>(xb, w_gin, g_in_b, qkvg_b, 256, 768, 0);
    attn_global_mfma<<<dim3(1024), 256, 0, stream>>>(qkvg_b, attng);
    // Output projections into comb ([8192,512] bf16: cols 0-255 global, 256-511 local)
    gemm_bf16<false, true><<<dim3(2, 64), 256, 0, stream>>>(attng, w_gout, g_out_b, comb, 256, 512, 0);
    gemm_bf16<false, true><<<dim3(2, 64), 256, 0, stream>>>(attnl, w_tout, t_out_b, comb, 256, 512, 256);
    // Fusion MLP
    gemm_bf16<true,  true><<<dim3(4, 64), 256, 0, stream>>>(comb, w_f1, fus_b1, h1, 512, 512, 0);
    gemm_bf16<false, false><<<dim3(2, 64), 256, 0, stream>>>(h1, w_f2, fus_b2, xf, 512, 256, 0);
    ln_residual<<<dim3(2048), 256, 0, stream>>>(x, xf, gn_g, gn_b, x2, x2b);
    // FFN
    gemm_bf16<true,  true><<<dim3(4, 64), 256, 0, stream>>>(x2b, w_n1, ffn_b1, h2, 256, 512, 0);
    gemm_bf16<false, false><<<dim3(2, 64), 256, 0, stream>>>(h2, w_n2, ffn_b2, xff, 512, 256, 0);
    ln_residual<<<dim3(2048), 256, 0, stream>>>(x2, xff, fn_g, fn_b, out, nullptr);
}

// Round 5
// 263.264 us; speedup vs baseline: 5.9346x; 1.0686x over previous
//
#include <hip/hip_runtime.h>

constexpr int Bb = 4;
constexpr int Ss = 2048;
constexpr int QSTR = 1536;   // combined qkv row stride (g 0..767, t 768..1535)

typedef __bf16 bf16x8 __attribute__((ext_vector_type(8)));
typedef __bf16 bf16x4 __attribute__((ext_vector_type(4)));
typedef float  f32x4  __attribute__((ext_vector_type(4)));

// async global->LDS, 16B per lane; dest = wave-uniform base + lane*16
__device__ __forceinline__ void glds16(const void* g, void* l) {
    __builtin_amdgcn_global_load_lds(
        (const __attribute__((address_space(1))) unsigned int*)g,
        (__attribute__((address_space(3))) unsigned int*)l, 16, 0, 0);
}

// ---------------------------------------------------------------------------
// convert_all: fp32 -> bf16 for x and the 8 weight matrices, one launch.
// ---------------------------------------------------------------------------
struct CvtArgs {
    const float* src[9];
    __bf16* dst[9];
    int start[10];
};

__global__ __launch_bounds__(256) void convert_all(CvtArgs a)
{
    int e = 0;
    const int bid = blockIdx.x;
#pragma unroll
    for (int i = 0; i < 8; i++) if (bid >= a.start[i + 1]) e = i + 1;
    const int idx = (bid - a.start[e]) * 256 + threadIdx.x;
    const float* s = a.src[e];
    float4 v0 = *(const float4*)&s[(size_t)idx * 8];
    float4 v1 = *(const float4*)&s[(size_t)idx * 8 + 4];
    bf16x8 o;
    o[0] = (__bf16)v0.x; o[1] = (__bf16)v0.y; o[2] = (__bf16)v0.z; o[3] = (__bf16)v0.w;
    o[4] = (__bf16)v1.x; o[5] = (__bf16)v1.y; o[6] = (__bf16)v1.z; o[7] = (__bf16)v1.w;
    *(bf16x8*)&a.dst[e][(size_t)idx * 8] = o;
}

// ---------------------------------------------------------------------------
// bf16 MFMA GEMM, 64x64 tile, BK=64, 4 waves (2x2 of 32x32).
// Staging via global_load_lds(16B) with XOR source swizzle: LDS slot (row,g)
// holds global chunk (row, g^(row&7)); frag reads land conflict-free.
// Dual bias: col < bsplit -> bias[col], else bias2[col-bsplit].
// ---------------------------------------------------------------------------
template<bool SILU, bool OUT_BF16>
__global__ __launch_bounds__(256) void gemm_bf16(
    const __bf16* __restrict__ A, const __bf16* __restrict__ W,
    const float* __restrict__ bias, const float* __restrict__ bias2, int bsplit,
    void* __restrict__ C, int K, int ldc, int coff)
{
    __shared__ __bf16 As[64 * 64];
    __shared__ __bf16 Ws[64 * 64];
    const int tid = threadIdx.x;
    const int lane = tid & 63;
    const int wv = tid >> 6;
    const int wm = (wv >> 1) * 32;
    const int wn = (wv & 1) * 32;
    const int qrow = lane & 15;
    const int quad = lane >> 4;
    const int n0 = blockIdx.x * 64;
    const int m0 = blockIdx.y * 64;

    f32x4 acc[2][2];
#pragma unroll
    for (int i = 0; i < 2; i++)
#pragma unroll
        for (int j = 0; j < 2; j++) acc[i][j] = {0.f, 0.f, 0.f, 0.f};

    for (int k0 = 0; k0 < K; k0 += 64) {
        __syncthreads();
        // stage A and W: 64 rows x 8 chunks(16B) each = 512 chunks; 2 wave-calls
        // per wave per matrix. chunk c -> row=c>>3, slot g=c&7, src col (g^(row&7)).
#pragma unroll
        for (int i = 0; i < 2; i++) {
            const int c = (wv * 2 + i) * 64 + lane;
            const int row = c >> 3, g = c & 7;
            const int gs = (g ^ (row & 7)) * 8;
            glds16(&A[(size_t)(m0 + row) * K + k0 + gs], &As[(wv * 2 + i) * 512]);
            glds16(&W[(size_t)(n0 + row) * K + k0 + gs], &Ws[(wv * 2 + i) * 512]);
        }
        __syncthreads();
#pragma unroll
        for (int ksub = 0; ksub < 2; ksub++) {
            bf16x8 af[2], bf[2];
#pragma unroll
            for (int mi = 0; mi < 2; mi++) {
                const int row = wm + mi * 16 + qrow;
                const int gl = ksub * 4 + quad;
                af[mi] = *(const bf16x8*)&As[row * 64 + (gl ^ (row & 7)) * 8];
            }
#pragma unroll
            for (int ni = 0; ni < 2; ni++) {
                const int row = wn + ni * 16 + qrow;
                const int gl = ksub * 4 + quad;
                bf[ni] = *(const bf16x8*)&Ws[row * 64 + (gl ^ (row & 7)) * 8];
            }
#pragma unroll
            for (int mi = 0; mi < 2; mi++)
#pragma unroll
                for (int ni = 0; ni < 2; ni++)
                    acc[mi][ni] = __builtin_amdgcn_mfma_f32_16x16x32_bf16(
                        af[mi], bf[ni], acc[mi][ni], 0, 0, 0);
        }
    }

    float bz[2];
#pragma unroll
    for (int ni = 0; ni < 2; ni++) {
        const int n = n0 + wn + ni * 16 + qrow;
        bz[ni] = (n < bsplit) ? bias[n] : bias2[n - bsplit];
    }

#pragma unroll
    for (int mi = 0; mi < 2; mi++) {
#pragma unroll
        for (int r = 0; r < 4; r++) {
            const int row = m0 + wm + mi * 16 + quad * 4 + r;
#pragma unroll
            for (int ni = 0; ni < 2; ni++) {
                float v = acc[mi][ni][r] + bz[ni];
                if (SILU) v = v / (1.f + __expf(-v));
                const int col = coff + n0 + wn + ni * 16 + qrow;
                if (OUT_BF16)
                    ((__bf16*)C)[(size_t)row * ldc + col] = (__bf16)v;
                else
                    ((float*)C)[(size_t)row * ldc + col] = v;
            }
        }
    }
}

// ---------------------------------------------------------------------------
// Global MHA via MFMA. 8 heads, hd=32, S=2048, no-max softmax (scores O(0.5)).
// qkv: combined bf16 [B*S,1536], global segment cols 0..767.
// Block: 4 waves x 16 queries. Grid 1024 = (b:4,h:8,qc:32).
// Per 64-key chunk: K via global_load_lds (packed [64][32]); V transposed
// manually [32][72]; 4 QK MFMAs -> 16 exp2 -> P [16][72] -> 4 PV MFMAs.
// ---------------------------------------------------------------------------
__global__ __launch_bounds__(256) void attn_global_mfma(
    const __bf16* __restrict__ qkv, __bf16* __restrict__ out)
{
    __shared__ __bf16 Kl[64 * 32];
    __shared__ __bf16 Vt[32 * 72];
    __shared__ __bf16 Pl[4][16 * 72];

    const int t = threadIdx.x;
    const int bid = blockIdx.x;
    const int qc = bid & 31;
    const int h  = (bid >> 5) & 7;
    const int b  = bid >> 8;
    const int bS = b * Ss;
    const int q0 = qc * 64;

    const int lane = t & 63;
    const int wv = t >> 6;
    const int qrow = lane & 15;
    const int quad = lane >> 4;
    const float cQ = 1.4426950408889634f * 0.17677669529663687f; // log2e/sqrt(32)

    bf16x8 qf;
    {
        bf16x8 qraw = *(const bf16x8*)(qkv +
            (size_t)(bS + q0 + wv * 16 + qrow) * QSTR + h * 32 + quad * 8);
#pragma unroll
        for (int i = 0; i < 8; i++) qf[i] = (__bf16)((float)qraw[i] * cQ);
    }

    f32x4 o0 = {0.f, 0.f, 0.f, 0.f};
    f32x4 o1 = {0.f, 0.f, 0.f, 0.f};
    float l[4] = {0.f, 0.f, 0.f, 0.f};
    const f32x4 z = {0.f, 0.f, 0.f, 0.f};

    // staging index precompute
    const int vkey = t & 63, vdg = t >> 6;          // V: key, dim-chunk
    const int kc_c = wv * 64 + lane;                // K chunks: this wave's chunk
    const int kkey = kc_c >> 2, kdg = kc_c & 3;

    for (int kc = 0; kc < 32; kc++) {
        __syncthreads();
        // K: 64 keys x 4 chunks(16B) = 256 chunks, 1 glds call per wave
        glds16(qkv + (size_t)(bS + kc * 64 + kkey) * QSTR + 256 + h * 32 + kdg * 8,
               &Kl[wv * 512]);
        // V transposed: [dim][key]
        {
            const __bf16* src = qkv + (size_t)(bS + kc * 64 + vkey) * QSTR + 512 + h * 32 + vdg * 8;
            bf16x8 v = *(const bf16x8*)src;
#pragma unroll
            for (int i = 0; i < 8; i++) Vt[(vdg * 8 + i) * 72 + vkey] = v[i];
        }
        __syncthreads();

        // 4 independent QK MFMAs over the 64 keys
        f32x4 s[4];
#pragma unroll
        for (int kg = 0; kg < 4; kg++) {
            bf16x8 kf = *(const bf16x8*)&Kl[(kg * 16 + qrow) * 32 + quad * 8];
            s[kg] = __builtin_amdgcn_mfma_f32_16x16x32_bf16(qf, kf, z, 0, 0, 0);
        }
        // 16 independent exp2s; P[q=quad*4+r][key=kg*16+qrow]
#pragma unroll
        for (int kg = 0; kg < 4; kg++) {
            float p0 = exp2f(s[kg][0]);
            float p1 = exp2f(s[kg][1]);
            float p2 = exp2f(s[kg][2]);
            float p3 = exp2f(s[kg][3]);
            l[0] += p0; l[1] += p1; l[2] += p2; l[3] += p3;
            __bf16* pw = &Pl[wv][kg * 16 + qrow];
            pw[(quad * 4 + 0) * 72] = (__bf16)p0;
            pw[(quad * 4 + 1) * 72] = (__bf16)p1;
            pw[(quad * 4 + 2) * 72] = (__bf16)p2;
            pw[(quad * 4 + 3) * 72] = (__bf16)p3;
        }
        // P A-frags (keys 0..31, 32..63) and V B-frags; 4 PV MFMAs
        bf16x8 pf0 = *(const bf16x8*)&Pl[wv][qrow * 72 + quad * 8];
        bf16x8 pf1 = *(const bf16x8*)&Pl[wv][qrow * 72 + 32 + quad * 8];
        bf16x8 vf00 = *(const bf16x8*)&Vt[qrow * 72 + quad * 8];            // d0-15,k0-31
        bf16x8 vf01 = *(const bf16x8*)&Vt[qrow * 72 + 32 + quad * 8];       // d0-15,k32-63
        bf16x8 vf10 = *(const bf16x8*)&Vt[(16 + qrow) * 72 + quad * 8];     // d16-31,k0-31
        bf16x8 vf11 = *(const bf16x8*)&Vt[(16 + qrow) * 72 + 32 + quad * 8];
        o0 = __builtin_amdgcn_mfma_f32_16x16x32_bf16(pf0, vf00, o0, 0, 0, 0);
        o1 = __builtin_amdgcn_mfma_f32_16x16x32_bf16(pf0, vf10, o1, 0, 0, 0);
        o0 = __builtin_amdgcn_mfma_f32_16x16x32_bf16(pf1, vf01, o0, 0, 0, 0);
        o1 = __builtin_amdgcn_mfma_f32_16x16x32_bf16(pf1, vf11, o1, 0, 0, 0);
    }

#pragma unroll
    for (int r = 0; r < 4; r++) {
#pragma unroll
        for (int off = 1; off < 16; off <<= 1)
            l[r] += __shfl_xor(l[r], off, 64);
    }
#pragma unroll
    for (int r = 0; r < 4; r++) {
        float iv = 1.f / l[r];
        const int row = q0 + wv * 16 + quad * 4 + r;
        __bf16* po = out + (size_t)(bS + row) * 256 + h * 32;
        po[qrow]      = (__bf16)(o0[r] * iv);
        po[16 + qrow] = (__bf16)(o1[r] * iv);
    }
}

// ---------------------------------------------------------------------------
// Local windowed MHA: 4 heads, hd=64, window 5. Wave per (b,s,h).
// Reads combined qkv (local segment at col 768).
// ---------------------------------------------------------------------------
__global__ __launch_bounds__(256) void attn_local(
    const __bf16* __restrict__ qkv, __bf16* __restrict__ out)
{
    const int lane = threadIdx.x & 63;
    const int w = blockIdx.x * 4 + (threadIdx.x >> 6);
    const int b = w >> 13;
    const int rem = w & 8191;
    const int s = rem >> 2;
    const int h = rem & 3;

    const float q = (float)qkv[(size_t)(b * Ss + s) * QSTR + 768 + h * 64 + lane];
    float sc[5], vv[5];
#pragma unroll
    for (int j = 0; j < 5; j++) {
        int pos = s + j - 2;
        bool valid = (pos >= 0) && (pos < Ss);
        int cpos = valid ? pos : 0;
        const size_t rb = (size_t)(b * Ss + cpos) * QSTR;
        float kj = valid ? (float)qkv[rb + 1024 + h * 64 + lane] : 0.f;
        vv[j] = valid ? (float)qkv[rb + 1280 + h * 64 + lane] : 0.f;
        float p = q * kj;
#pragma unroll
        for (int off = 32; off > 0; off >>= 1) p += __shfl_xor(p, off, 64);
        sc[j] = valid ? p * 0.125f : -1e30f;
    }
    float m = sc[0];
#pragma unroll
    for (int j = 1; j < 5; j++) m = fmaxf(m, sc[j]);
    float l = 0.f, o = 0.f;
#pragma unroll
    for (int j = 0; j < 5; j++) {
        float p = __expf(sc[j] - m);
        l += p; o += p * vv[j];
    }
    out[(size_t)(b * Ss + s) * 256 + h * 64 + lane] = (__bf16)(o / l);
}

// ---------------------------------------------------------------------------
// out = LayerNorm(a + r) * g + be over last dim (256). Wave per token.
// ---------------------------------------------------------------------------
__global__ __launch_bounds__(256) void ln_residual(
    const float* __restrict__ a, const float* __restrict__ r,
    const float* __restrict__ g, const float* __restrict__ be,
    float* __restrict__ out, __bf16* __restrict__ ob)
{
    const int lane = threadIdx.x & 63;
    const int tok = blockIdx.x * 4 + (threadIdx.x >> 6);
    float4 xa = ((const float4*)a)[(size_t)tok * 64 + lane];
    float4 xr = ((const float4*)r)[(size_t)tok * 64 + lane];
    float4 x;
    x.x = xa.x + xr.x; x.y = xa.y + xr.y; x.z = xa.z + xr.z; x.w = xa.w + xr.w;
    float sum = x.x + x.y + x.z + x.w;
#pragma unroll
    for (int off = 32; off > 0; off >>= 1) sum += __shfl_xor(sum, off, 64);
    float mu = sum * (1.f / 256.f);
    float4 c;
    c.x = x.x - mu; c.y = x.y - mu; c.z = x.z - mu; c.w = x.w - mu;
    float sq = c.x * c.x + c.y * c.y + c.z * c.z + c.w * c.w;
#pragma unroll
    for (int off = 32; off > 0; off >>= 1) sq += __shfl_xor(sq, off, 64);
    float rs = rsqrtf(sq * (1.f / 256.f) + 1e-5f);
    float4 gg = ((const float4*)g)[lane];
    float4 bb = ((const float4*)be)[lane];
    float4 o;
    o.x = c.x * rs * gg.x + bb.x; o.y = c.y * rs * gg.y + bb.y;
    o.z = c.z * rs * gg.z + bb.z; o.w = c.w * rs * gg.w + bb.w;
    ((float4*)out)[(size_t)tok * 64 + lane] = o;
    if (ob) {
        bf16x4 hh;
        hh[0] = (__bf16)o.x; hh[1] = (__bf16)o.y; hh[2] = (__bf16)o.z; hh[3] = (__bf16)o.w;
        *(bf16x4*)&ob[(size_t)tok * 256 + lane * 4] = hh;
    }
}

// ---------------------------------------------------------------------------
extern "C" void kernel_launch(void* const* d_in, const int* in_sizes, int n_in,
                              void* d_out, int out_size, void* d_ws, size_t ws_size,
                              hipStream_t stream)
{
    const float* x      = (const float*)d_in[0];
    const float* g_in_w = (const float*)d_in[1];
    const float* g_in_b = (const float*)d_in[2];
    const float* g_out_w= (const float*)d_in[3];
    const float* g_out_b= (const float*)d_in[4];
    const float* t_in_w = (const float*)d_in[5];
    const float* t_in_b = (const float*)d_in[6];
    const float* t_out_w= (const float*)d_in[7];
    const float* t_out_b= (const float*)d_in[8];
    const float* fus_w1 = (const float*)d_in[9];
    const float* fus_b1 = (const float*)d_in[10];
    const float* fus_w2 = (const float*)d_in[11];
    const float* fus_b2 = (const float*)d_in[12];
    const float* ffn_w1 = (const float*)d_in[13];
    const float* ffn_b1 = (const float*)d_in[14];
    const float* ffn_w2 = (const float*)d_in[15];
    const float* ffn_b2 = (const float*)d_in[16];
    const float* gn_g   = (const float*)d_in[17];
    const float* gn_b   = (const float*)d_in[18];
    const float* fn_g   = (const float*)d_in[19];
    const float* fn_b   = (const float*)d_in[20];
    float* out = (float*)d_out;
    float* ws  = (float*)d_ws;

    // ws layout in f32 slots (peak 19,464,192 slots = 77.9 MB; ws = 84 MB known-safe)
    __bf16* xb     = (__bf16*)(ws);                 // [0, 1048576)
    __bf16* wb     = (__bf16*)(ws + 1048576);       // [1048576, 1638400)
    __bf16* qkvgl  = (__bf16*)(ws + 1638400);       // [1638400, 7929856)  8192x1536
    __bf16* attng  = (__bf16*)(ws + 7929856);       // [7929856, 8978432)
    __bf16* attnl  = (__bf16*)(ws + 8978432);       // [8978432, 10027008)
    __bf16* comb   = (__bf16*)(ws + 10027008);      // [10027008, 12124160) 8192x512
    __bf16* h1     = (__bf16*)(ws + 12124160);      // [12124160, 14221312) 8192x512
    float*  xf     = ws + 14221312;                 // [14221312, 16318464) fp32
    float*  x2     = ws + 16318464;                 // [16318464, 18415616) fp32
    __bf16* x2b    = (__bf16*)(ws + 18415616);      // [18415616, 19464192)
    __bf16* h2     = h1;                            // reuse
    float*  xff    = xf;                            // reuse

    __bf16* w_gin  = wb;              // [1536x256] combined (g rows 0-767, t 768-1535)
    __bf16* w_gout = wb + 393216;
    __bf16* w_tout = wb + 458752;
    __bf16* w_f1   = wb + 524288;
    __bf16* w_f2   = wb + 786432;
    __bf16* w_n1   = wb + 917504;
    __bf16* w_n2   = wb + 1048576;

    CvtArgs ca;
    ca.src[0] = x;      ca.dst[0] = xb;
    ca.src[1] = g_in_w; ca.dst[1] = wb;
    ca.src[2] = t_in_w; ca.dst[2] = wb + 196608;
    ca.src[3] = g_out_w;ca.dst[3] = w_gout;
    ca.src[4] = t_out_w;ca.dst[4] = w_tout;
    ca.src[5] = fus_w1; ca.dst[5] = w_f1;
    ca.src[6] = fus_w2; ca.dst[6] = w_f2;
    ca.src[7] = ffn_w1; ca.dst[7] = w_n1;
    ca.src[8] = ffn_w2; ca.dst[8] = w_n2;
    int st[10] = {0, 1024, 1120, 1216, 1248, 1280, 1408, 1472, 1536, 1600};
    for (int i = 0; i < 10; i++) ca.start[i] = st[i];

    convert_all<<<dim3(1600), 256, 0, stream>>>(ca);

    const int BIG = 1 << 30;
    // Combined QKV projection: M=8192, N=1536, K=256 -> qkvgl
    gemm_bf16<false, true><<<dim3(24, 128), 256, 0, stream>>>(
        xb, w_gin, g_in_b, t_in_b, 768, qkvgl, 256, QSTR, 0);
    attn_local<<<dim3(8192), 256, 0, stream>>>(qkvgl, attnl);
    attn_global_mfma<<<dim3(1024), 256, 0, stream>>>(qkvgl, attng);
    // Output projections into comb [8192,512]
    gemm_bf16<false, true><<<dim3(4, 128), 256, 0, stream>>>(
        attng, w_gout, g_out_b, g_out_b, BIG, comb, 256, 512, 0);
    gemm_bf16<false, true><<<dim3(4, 128), 256, 0, stream>>>(
        attnl, w_tout, t_out_b, t_out_b, BIG, comb, 256, 512, 256);
    // Fusion MLP
    gemm_bf16<true,  true><<<dim3(8, 128), 256, 0, stream>>>(
        comb, w_f1, fus_b1, fus_b1, BIG, h1, 512, 512, 0);
    gemm_bf16<false, false><<<dim3(4, 128), 256, 0, stream>>>(
        h1, w_f2, fus_b2, fus_b2, BIG, xf, 512, 256, 0);
    ln_residual<<<dim3(2048), 256, 0, stream>>>(x, xf, gn_g, gn_b, x2, x2b);
    // FFN
    gemm_bf16<true,  true><<<dim3(8, 128), 256, 0, stream>>>(
        x2b, w_n1, ffn_b1, ffn_b1, BIG, h2, 256, 512, 0);
    gemm_bf16<false, false><<<dim3(4, 128), 256, 0, stream>>>(
        h2, w_n2, ffn_b2, ffn_b2, BIG, xff, 512, 256, 0);
    ln_residual<<<dim3(2048), 256, 0, stream>>>(x2, xff, fn_g, fn_b, out, nullptr);
}

// Round 6
// 257.872 us; speedup vs baseline: 6.0587x; 1.0209x over previous
//
#include <hip/hip_runtime.h>

constexpr int Bb = 4;
constexpr int Ss = 2048;
constexpr int QSTR = 1536;   // combined qkv row stride (g 0..767, t 768..1535)

typedef __bf16 bf16x8 __attribute__((ext_vector_type(8)));
typedef __bf16 bf16x4 __attribute__((ext_vector_type(4)));
typedef float  f32x4  __attribute__((ext_vector_type(4)));

// async global->LDS, 16B per lane; dest = wave-uniform base + lane*16
__device__ __forceinline__ void glds16(const void* g, void* l) {
    __builtin_amdgcn_global_load_lds(
        (const __attribute__((address_space(1))) unsigned int*)g,
        (__attribute__((address_space(3))) unsigned int*)l, 16, 0, 0);
}

// ---------------------------------------------------------------------------
// convert_all: fp32 -> bf16 for x and the 8 weight matrices, one launch.
// ---------------------------------------------------------------------------
struct CvtArgs {
    const float* src[9];
    __bf16* dst[9];
    int start[10];
};

__global__ __launch_bounds__(256) void convert_all(CvtArgs a)
{
    int e = 0;
    const int bid = blockIdx.x;
#pragma unroll
    for (int i = 0; i < 8; i++) if (bid >= a.start[i + 1]) e = i + 1;
    const int idx = (bid - a.start[e]) * 256 + threadIdx.x;
    const float* s = a.src[e];
    float4 v0 = *(const float4*)&s[(size_t)idx * 8];
    float4 v1 = *(const float4*)&s[(size_t)idx * 8 + 4];
    bf16x8 o;
    o[0] = (__bf16)v0.x; o[1] = (__bf16)v0.y; o[2] = (__bf16)v0.z; o[3] = (__bf16)v0.w;
    o[4] = (__bf16)v1.x; o[5] = (__bf16)v1.y; o[6] = (__bf16)v1.z; o[7] = (__bf16)v1.w;
    *(bf16x8*)&a.dst[e][(size_t)idx * 8] = o;
}

// ---------------------------------------------------------------------------
// bf16 MFMA GEMM, 64x64 tile, BK=64, 4 waves (2x2 of 32x32).  (unchanged R5)
// ---------------------------------------------------------------------------
template<bool SILU, bool OUT_BF16>
__global__ __launch_bounds__(256) void gemm_bf16(
    const __bf16* __restrict__ A, const __bf16* __restrict__ W,
    const float* __restrict__ bias, const float* __restrict__ bias2, int bsplit,
    void* __restrict__ C, int K, int ldc, int coff)
{
    __shared__ __bf16 As[64 * 64];
    __shared__ __bf16 Ws[64 * 64];
    const int tid = threadIdx.x;
    const int lane = tid & 63;
    const int wv = tid >> 6;
    const int wm = (wv >> 1) * 32;
    const int wn = (wv & 1) * 32;
    const int qrow = lane & 15;
    const int quad = lane >> 4;
    const int n0 = blockIdx.x * 64;
    const int m0 = blockIdx.y * 64;

    f32x4 acc[2][2];
#pragma unroll
    for (int i = 0; i < 2; i++)
#pragma unroll
        for (int j = 0; j < 2; j++) acc[i][j] = {0.f, 0.f, 0.f, 0.f};

    for (int k0 = 0; k0 < K; k0 += 64) {
        __syncthreads();
#pragma unroll
        for (int i = 0; i < 2; i++) {
            const int c = (wv * 2 + i) * 64 + lane;
            const int row = c >> 3, g = c & 7;
            const int gs = (g ^ (row & 7)) * 8;
            glds16(&A[(size_t)(m0 + row) * K + k0 + gs], &As[(wv * 2 + i) * 512]);
            glds16(&W[(size_t)(n0 + row) * K + k0 + gs], &Ws[(wv * 2 + i) * 512]);
        }
        __syncthreads();
#pragma unroll
        for (int ksub = 0; ksub < 2; ksub++) {
            bf16x8 af[2], bf[2];
#pragma unroll
            for (int mi = 0; mi < 2; mi++) {
                const int row = wm + mi * 16 + qrow;
                const int gl = ksub * 4 + quad;
                af[mi] = *(const bf16x8*)&As[row * 64 + (gl ^ (row & 7)) * 8];
            }
#pragma unroll
            for (int ni = 0; ni < 2; ni++) {
                const int row = wn + ni * 16 + qrow;
                const int gl = ksub * 4 + quad;
                bf[ni] = *(const bf16x8*)&Ws[row * 64 + (gl ^ (row & 7)) * 8];
            }
#pragma unroll
            for (int mi = 0; mi < 2; mi++)
#pragma unroll
                for (int ni = 0; ni < 2; ni++)
                    acc[mi][ni] = __builtin_amdgcn_mfma_f32_16x16x32_bf16(
                        af[mi], bf[ni], acc[mi][ni], 0, 0, 0);
        }
    }

    float bz[2];
#pragma unroll
    for (int ni = 0; ni < 2; ni++) {
        const int n = n0 + wn + ni * 16 + qrow;
        bz[ni] = (n < bsplit) ? bias[n] : bias2[n - bsplit];
    }

#pragma unroll
    for (int mi = 0; mi < 2; mi++) {
#pragma unroll
        for (int r = 0; r < 4; r++) {
            const int row = m0 + wm + mi * 16 + quad * 4 + r;
#pragma unroll
            for (int ni = 0; ni < 2; ni++) {
                float v = acc[mi][ni][r] + bz[ni];
                if (SILU) v = v / (1.f + __expf(-v));
                const int col = coff + n0 + wn + ni * 16 + qrow;
                if (OUT_BF16)
                    ((__bf16*)C)[(size_t)row * ldc + col] = (__bf16)v;
                else
                    ((float*)C)[(size_t)row * ldc + col] = v;
            }
        }
    }
}

// ---------------------------------------------------------------------------
// Global MHA split-K partials. No-max softmax makes partials associative:
// each block accumulates unnormalized O and l over half the keys.
// Grid 2048 = (b:4, h:8, qc:32, sp:2); block = 4 waves x 16 queries.
// l computed via MFMA against an all-ones B-frag (row-sum trick; no shuffle
// reduce). Partials: Op[sp][gid][32] fp32, Lp[sp][gid], gid=(b*8+h)*2048+q.
// ---------------------------------------------------------------------------
__global__ __launch_bounds__(256) void attn_global_part(
    const __bf16* __restrict__ qkv, float* __restrict__ Op, float* __restrict__ Lp)
{
    __shared__ __bf16 Kl[64 * 32];
    __shared__ __bf16 Vt[32 * 72];
    __shared__ __bf16 Pl[4][16 * 72];

    const int t = threadIdx.x;
    const int bid = blockIdx.x;
    const int sp = bid & 1;
    const int qc = (bid >> 1) & 31;
    const int h  = (bid >> 6) & 7;
    const int b  = bid >> 9;
    const int bS = b * Ss;
    const int q0 = qc * 64;

    const int lane = t & 63;
    const int wv = t >> 6;
    const int qrow = lane & 15;
    const int quad = lane >> 4;
    const float cQ = 1.4426950408889634f * 0.17677669529663687f; // log2e/sqrt(32)

    bf16x8 qf;
    {
        bf16x8 qraw = *(const bf16x8*)(qkv +
            (size_t)(bS + q0 + wv * 16 + qrow) * QSTR + h * 32 + quad * 8);
#pragma unroll
        for (int i = 0; i < 8; i++) qf[i] = (__bf16)((float)qraw[i] * cQ);
    }
    bf16x8 ones;
#pragma unroll
    for (int i = 0; i < 8; i++) ones[i] = (__bf16)1.0f;

    f32x4 o0 = {0.f, 0.f, 0.f, 0.f};
    f32x4 o1 = {0.f, 0.f, 0.f, 0.f};
    f32x4 lac = {0.f, 0.f, 0.f, 0.f};
    const f32x4 z = {0.f, 0.f, 0.f, 0.f};

    // staging index precompute
    const int vkey = t & 63, vdg = t >> 6;          // V: key, dim-chunk
    const int kc_c = wv * 64 + lane;                // K chunks: this wave's chunk
    const int kkey = kc_c >> 2, kdg = kc_c & 3;

    for (int kc = sp * 16; kc < sp * 16 + 16; kc++) {
        __syncthreads();
        // K: 64 keys x 4 chunks(16B) = 256 chunks, 1 glds call per wave
        glds16(qkv + (size_t)(bS + kc * 64 + kkey) * QSTR + 256 + h * 32 + kdg * 8,
               &Kl[wv * 512]);
        // V transposed: [dim][key]
        {
            const __bf16* src = qkv + (size_t)(bS + kc * 64 + vkey) * QSTR + 512 + h * 32 + vdg * 8;
            bf16x8 v = *(const bf16x8*)src;
#pragma unroll
            for (int i = 0; i < 8; i++) Vt[(vdg * 8 + i) * 72 + vkey] = v[i];
        }
        __syncthreads();

        // 4 independent QK MFMAs over the 64 keys
        f32x4 s[4];
#pragma unroll
        for (int kg = 0; kg < 4; kg++) {
            bf16x8 kf = *(const bf16x8*)&Kl[(kg * 16 + qrow) * 32 + quad * 8];
            s[kg] = __builtin_amdgcn_mfma_f32_16x16x32_bf16(qf, kf, z, 0, 0, 0);
        }
        // 16 independent exp2s; P[q=quad*4+r][key=kg*16+qrow]
#pragma unroll
        for (int kg = 0; kg < 4; kg++) {
            float p0 = exp2f(s[kg][0]);
            float p1 = exp2f(s[kg][1]);
            float p2 = exp2f(s[kg][2]);
            float p3 = exp2f(s[kg][3]);
            __bf16* pw = &Pl[wv][kg * 16 + qrow];
            pw[(quad * 4 + 0) * 72] = (__bf16)p0;
            pw[(quad * 4 + 1) * 72] = (__bf16)p1;
            pw[(quad * 4 + 2) * 72] = (__bf16)p2;
            pw[(quad * 4 + 3) * 72] = (__bf16)p3;
        }
        // P A-frags (keys 0..31, 32..63) and V B-frags; 4 PV MFMAs + 2 l MFMAs
        bf16x8 pf0 = *(const bf16x8*)&Pl[wv][qrow * 72 + quad * 8];
        bf16x8 pf1 = *(const bf16x8*)&Pl[wv][qrow * 72 + 32 + quad * 8];
        bf16x8 vf00 = *(const bf16x8*)&Vt[qrow * 72 + quad * 8];
        bf16x8 vf01 = *(const bf16x8*)&Vt[qrow * 72 + 32 + quad * 8];
        bf16x8 vf10 = *(const bf16x8*)&Vt[(16 + qrow) * 72 + quad * 8];
        bf16x8 vf11 = *(const bf16x8*)&Vt[(16 + qrow) * 72 + 32 + quad * 8];
        o0 = __builtin_amdgcn_mfma_f32_16x16x32_bf16(pf0, vf00, o0, 0, 0, 0);
        o1 = __builtin_amdgcn_mfma_f32_16x16x32_bf16(pf0, vf10, o1, 0, 0, 0);
        lac = __builtin_amdgcn_mfma_f32_16x16x32_bf16(pf0, ones, lac, 0, 0, 0);
        o0 = __builtin_amdgcn_mfma_f32_16x16x32_bf16(pf1, vf01, o0, 0, 0, 0);
        o1 = __builtin_amdgcn_mfma_f32_16x16x32_bf16(pf1, vf11, o1, 0, 0, 0);
        lac = __builtin_amdgcn_mfma_f32_16x16x32_bf16(pf1, ones, lac, 0, 0, 0);
    }

    // write unnormalized partials; lac[r] already = row-sum (replicated per col)
#pragma unroll
    for (int r = 0; r < 4; r++) {
        const int row = q0 + wv * 16 + quad * 4 + r;
        const int gid = (b * 8 + h) * 2048 + row;
        float* po = Op + (size_t)sp * 2097152 + (size_t)gid * 32;
        po[qrow]      = o0[r];
        po[16 + qrow] = o1[r];
        if (qrow == 0) Lp[sp * 65536 + gid] = lac[r];
    }
}

// ---------------------------------------------------------------------------
// Combine 2 split partials -> attng bf16 [B,S,256].
// Thread t: gid = t>>3 (query-head id), dg = t&7 (float4 dim group).
// ---------------------------------------------------------------------------
__global__ __launch_bounds__(256) void attn_combine(
    const float* __restrict__ Op, const float* __restrict__ Lp,
    __bf16* __restrict__ out)
{
    const int t = blockIdx.x * 256 + threadIdx.x;   // 0 .. 524287
    const int gid = t >> 3;
    const int dg = t & 7;
    const int b = gid >> 14;
    const int h = (gid >> 11) & 7;
    const int q = gid & 2047;

    const float li = 1.f / (Lp[gid] + Lp[65536 + gid]);
    float4 a = *(const float4*)&Op[(size_t)gid * 32 + dg * 4];
    float4 c = *(const float4*)&Op[2097152 + (size_t)gid * 32 + dg * 4];
    bf16x4 r;
    r[0] = (__bf16)((a.x + c.x) * li);
    r[1] = (__bf16)((a.y + c.y) * li);
    r[2] = (__bf16)((a.z + c.z) * li);
    r[3] = (__bf16)((a.w + c.w) * li);
    *(bf16x4*)&out[(size_t)(b * Ss + q) * 256 + h * 32 + dg * 4] = r;
}

// ---------------------------------------------------------------------------
// Local windowed MHA: 4 heads, hd=64, window 5. Wave per (b,s,h).
// ---------------------------------------------------------------------------
__global__ __launch_bounds__(256) void attn_local(
    const __bf16* __restrict__ qkv, __bf16* __restrict__ out)
{
    const int lane = threadIdx.x & 63;
    const int w = blockIdx.x * 4 + (threadIdx.x >> 6);
    const int b = w >> 13;
    const int rem = w & 8191;
    const int s = rem >> 2;
    const int h = rem & 3;

    const float q = (float)qkv[(size_t)(b * Ss + s) * QSTR + 768 + h * 64 + lane];
    float sc[5], vv[5];
#pragma unroll
    for (int j = 0; j < 5; j++) {
        int pos = s + j - 2;
        bool valid = (pos >= 0) && (pos < Ss);
        int cpos = valid ? pos : 0;
        const size_t rb = (size_t)(b * Ss + cpos) * QSTR;
        float kj = valid ? (float)qkv[rb + 1024 + h * 64 + lane] : 0.f;
        vv[j] = valid ? (float)qkv[rb + 1280 + h * 64 + lane] : 0.f;
        float p = q * kj;
#pragma unroll
        for (int off = 32; off > 0; off >>= 1) p += __shfl_xor(p, off, 64);
        sc[j] = valid ? p * 0.125f : -1e30f;
    }
    float m = sc[0];
#pragma unroll
    for (int j = 1; j < 5; j++) m = fmaxf(m, sc[j]);
    float l = 0.f, o = 0.f;
#pragma unroll
    for (int j = 0; j < 5; j++) {
        float p = __expf(sc[j] - m);
        l += p; o += p * vv[j];
    }
    out[(size_t)(b * Ss + s) * 256 + h * 64 + lane] = (__bf16)(o / l);
}

// ---------------------------------------------------------------------------
// out = LayerNorm(a + r) * g + be over last dim (256). Wave per token.
// ---------------------------------------------------------------------------
__global__ __launch_bounds__(256) void ln_residual(
    const float* __restrict__ a, const float* __restrict__ r,
    const float* __restrict__ g, const float* __restrict__ be,
    float* __restrict__ out, __bf16* __restrict__ ob)
{
    const int lane = threadIdx.x & 63;
    const int tok = blockIdx.x * 4 + (threadIdx.x >> 6);
    float4 xa = ((const float4*)a)[(size_t)tok * 64 + lane];
    float4 xr = ((const float4*)r)[(size_t)tok * 64 + lane];
    float4 x;
    x.x = xa.x + xr.x; x.y = xa.y + xr.y; x.z = xa.z + xr.z; x.w = xa.w + xr.w;
    float sum = x.x + x.y + x.z + x.w;
#pragma unroll
    for (int off = 32; off > 0; off >>= 1) sum += __shfl_xor(sum, off, 64);
    float mu = sum * (1.f / 256.f);
    float4 c;
    c.x = x.x - mu; c.y = x.y - mu; c.z = x.z - mu; c.w = x.w - mu;
    float sq = c.x * c.x + c.y * c.y + c.z * c.z + c.w * c.w;
#pragma unroll
    for (int off = 32; off > 0; off >>= 1) sq += __shfl_xor(sq, off, 64);
    float rs = rsqrtf(sq * (1.f / 256.f) + 1e-5f);
    float4 gg = ((const float4*)g)[lane];
    float4 bb = ((const float4*)be)[lane];
    float4 o;
    o.x = c.x * rs * gg.x + bb.x; o.y = c.y * rs * gg.y + bb.y;
    o.z = c.z * rs * gg.z + bb.z; o.w = c.w * rs * gg.w + bb.w;
    ((float4*)out)[(size_t)tok * 64 + lane] = o;
    if (ob) {
        bf16x4 hh;
        hh[0] = (__bf16)o.x; hh[1] = (__bf16)o.y; hh[2] = (__bf16)o.z; hh[3] = (__bf16)o.w;
        *(bf16x4*)&ob[(size_t)tok * 256 + lane * 4] = hh;
    }
}

// ---------------------------------------------------------------------------
extern "C" void kernel_launch(void* const* d_in, const int* in_sizes, int n_in,
                              void* d_out, int out_size, void* d_ws, size_t ws_size,
                              hipStream_t stream)
{
    const float* x      = (const float*)d_in[0];
    const float* g_in_w = (const float*)d_in[1];
    const float* g_in_b = (const float*)d_in[2];
    const float* g_out_w= (const float*)d_in[3];
    const float* g_out_b= (const float*)d_in[4];
    const float* t_in_w = (const float*)d_in[5];
    const float* t_in_b = (const float*)d_in[6];
    const float* t_out_w= (const float*)d_in[7];
    const float* t_out_b= (const float*)d_in[8];
    const float* fus_w1 = (const float*)d_in[9];
    const float* fus_b1 = (const float*)d_in[10];
    const float* fus_w2 = (const float*)d_in[11];
    const float* fus_b2 = (const float*)d_in[12];
    const float* ffn_w1 = (const float*)d_in[13];
    const float* ffn_b1 = (const float*)d_in[14];
    const float* ffn_w2 = (const float*)d_in[15];
    const float* ffn_b2 = (const float*)d_in[16];
    const float* gn_g   = (const float*)d_in[17];
    const float* gn_b   = (const float*)d_in[18];
    const float* fn_g   = (const float*)d_in[19];
    const float* fn_b   = (const float*)d_in[20];
    float* out = (float*)d_out;
    float* ws  = (float*)d_ws;

    // ws layout in f32 slots (peak 19,464,192 slots = 77.9 MB; 84 MB known-safe)
    __bf16* xb     = (__bf16*)(ws);                 // [0, 1048576)
    __bf16* wb     = (__bf16*)(ws + 1048576);       // [1048576, 1638400)
    __bf16* qkvgl  = (__bf16*)(ws + 1638400);       // [1638400, 7929856)  8192x1536
    __bf16* attng  = (__bf16*)(ws + 7929856);       // [7929856, 8978432)
    __bf16* attnl  = (__bf16*)(ws + 8978432);       // [8978432, 10027008)
    __bf16* comb   = (__bf16*)(ws + 10027008);      // [10027008, 12124160) 8192x512
    __bf16* h1     = (__bf16*)(ws + 12124160);      // [12124160, 14221312) 8192x512
    float*  xf     = ws + 14221312;                 // [14221312, 16318464) fp32
    float*  x2     = ws + 16318464;                 // [16318464, 18415616) fp32
    __bf16* x2b    = (__bf16*)(ws + 18415616);      // [18415616, 19464192)
    __bf16* h2     = h1;                            // reuse
    float*  xff    = xf;                            // reuse
    // attention partials (live only between attn_global_part and attn_combine;
    // overlap comb+h1 and the first slots of xf, all written later):
    float* Op = ws + 10027008;                      // 2 x 65536 x 32 fp32
    float* Lp = ws + 14221312;                      // 2 x 65536 fp32

    __bf16* w_gin  = wb;              // [1536x256] combined (g rows 0-767, t 768-1535)
    __bf16* w_gout = wb + 393216;
    __bf16* w_tout = wb + 458752;
    __bf16* w_f1   = wb + 524288;
    __bf16* w_f2   = wb + 786432;
    __bf16* w_n1   = wb + 917504;
    __bf16* w_n2   = wb + 1048576;

    CvtArgs ca;
    ca.src[0] = x;      ca.dst[0] = xb;
    ca.src[1] = g_in_w; ca.dst[1] = wb;
    ca.src[2] = t_in_w; ca.dst[2] = wb + 196608;
    ca.src[3] = g_out_w;ca.dst[3] = w_gout;
    ca.src[4] = t_out_w;ca.dst[4] = w_tout;
    ca.src[5] = fus_w1; ca.dst[5] = w_f1;
    ca.src[6] = fus_w2; ca.dst[6] = w_f2;
    ca.src[7] = ffn_w1; ca.dst[7] = w_n1;
    ca.src[8] = ffn_w2; ca.dst[8] = w_n2;
    int st[10] = {0, 1024, 1120, 1216, 1248, 1280, 1408, 1472, 1536, 1600};
    for (int i = 0; i < 10; i++) ca.start[i] = st[i];

    convert_all<<<dim3(1600), 256, 0, stream>>>(ca);

    const int BIG = 1 << 30;
    // Combined QKV projection: M=8192, N=1536, K=256 -> qkvgl
    gemm_bf16<false, true><<<dim3(24, 128), 256, 0, stream>>>(
        xb, w_gin, g_in_b, t_in_b, 768, qkvgl, 256, QSTR, 0);
    attn_local<<<dim3(8192), 256, 0, stream>>>(qkvgl, attnl);
    // Global attention: split-K x2 partials + combine
    attn_global_part<<<dim3(2048), 256, 0, stream>>>(qkvgl, Op, Lp);
    attn_combine<<<dim3(2048), 256, 0, stream>>>(Op, Lp, attng);
    // Output projections into comb [8192,512]
    gemm_bf16<false, true><<<dim3(4, 128), 256, 0, stream>>>(
        attng, w_gout, g_out_b, g_out_b, BIG, comb, 256, 512, 0);
    gemm_bf16<false, true><<<dim3(4, 128), 256, 0, stream>>>(
        attnl, w_tout, t_out_b, t_out_b, BIG, comb, 256, 512, 256);
    // Fusion MLP
    gemm_bf16<true,  true><<<dim3(8, 128), 256, 0, stream>>>(
        comb, w_f1, fus_b1, fus_b1, BIG, h1, 512, 512, 0);
    gemm_bf16<false, false><<<dim3(4, 128), 256, 0, stream>>>(
        h1, w_f2, fus_b2, fus_b2, BIG, xf, 512, 256, 0);
    ln_residual<<<dim3(2048), 256, 0, stream>>>(x, xf, gn_g, gn_b, x2, x2b);
    // FFN
    gemm_bf16<true,  true><<<dim3(8, 128), 256, 0, stream>>>(
        x2b, w_n1, ffn_b1, ffn_b1, BIG, h2, 256, 512, 0);
    gemm_bf16<false, false><<<dim3(4, 128), 256, 0, stream>>>(
        h2, w_n2, ffn_b2, ffn_b2, BIG, xff, 512, 256, 0);
    ln_residual<<<dim3(2048), 256, 0, stream>>>(x2, xff, fn_g, fn_b, out, nullptr);
}